// Round 4
// baseline (1963.864 us; speedup 1.0000x reference)
//
#include <hip/hip_runtime.h>
#include <hip/hip_bf16.h>

// L=256, B=32, H=8, d_head=64, m=256, feature dim 2m=512, D_MODEL=512
#define L_SEQ 256
#define B_SZ  32
#define NH    8
#define DH    64
#define DM    512
#define FD    512
#define PM    256
#define ROWS  8192
#define QKVN  2048

typedef __bf16 bf16x8 __attribute__((ext_vector_type(8)));
typedef float f32x4 __attribute__((ext_vector_type(4)));
#define MFMA16(a, b, c) __builtin_amdgcn_mfma_f32_16x16x32_bf16((a), (b), (c), 0, 0, 0)

static __device__ __forceinline__ void stmix(void* p, long i, float v, int f32) {
  if (f32) ((float*)p)[i] = v;
  else     ((__bf16*)p)[i] = (__bf16)v;
}

// ---------------------------------------------------------------------------
// P0: dtype probe (validated round 2/3). bf16 N(0,1): no exponent >= 0xA0;
// f32-as-u16 odd halves: ~37% land there.
// ---------------------------------------------------------------------------
__global__ void probe_dtype(const unsigned short* __restrict__ hbits, int* __restrict__ flag) {
  __shared__ int red[256];
  const int tid = threadIdx.x;
  int cnt = 0;
  for (int i = 0; i < 16; ++i) {
    const unsigned short u = hbits[tid * 16 + i];
    const int e = (u >> 7) & 0xFF;
    if (e >= 0xA0) ++cnt;
  }
  red[tid] = cnt; __syncthreads();
  for (int s = 128; s > 0; s >>= 1) { if (tid < s) red[tid] += red[tid + s]; __syncthreads(); }
  if (tid == 0) flag[0] = (red[0] >= 64) ? 1 : 0;
}

// ---------------------------------------------------------------------------
// C0: convert any input array to bf16 with the dtype branch hoisted (uniform,
// once per thread) and fully vectorized loads. 8 elements/thread.
// ---------------------------------------------------------------------------
__global__ __launch_bounds__(256) void cvt_bf16(const void* __restrict__ src,
                                                __bf16* __restrict__ dst,
                                                const int* __restrict__ flag, int n8) {
  const int i = blockIdx.x * 256 + threadIdx.x;
  if (i >= n8) return;
  if (flag[0]) {
    const f32x4* s = (const f32x4*)src;
    const f32x4 a = s[i * 2], b = s[i * 2 + 1];
    bf16x8 t;
    t[0] = (__bf16)a[0]; t[1] = (__bf16)a[1]; t[2] = (__bf16)a[2]; t[3] = (__bf16)a[3];
    t[4] = (__bf16)b[0]; t[5] = (__bf16)b[1]; t[6] = (__bf16)b[2]; t[7] = (__bf16)b[3];
    *reinterpret_cast<bf16x8*>(dst + (long)i * 8) = t;
  } else {
    *reinterpret_cast<bf16x8*>(dst + (long)i * 8) = ((const bf16x8*)src)[i];
  }
}

// ---------------------------------------------------------------------------
// T0: dst[n][m] = src[m][n] as bf16. Branch hoisted around whole load loop.
// ---------------------------------------------------------------------------
__global__ __launch_bounds__(256) void transpose_bf(const void* __restrict__ src,
                                                    const int* __restrict__ flag,
                                                    __bf16* __restrict__ dst, int M, int N) {
  __shared__ float T[64][69];
  const int n0 = blockIdx.x * 64, m0 = blockIdx.y * 64;
  const int tid = threadIdx.x;
  if (flag[0]) {
    const float* s = (const float*)src;
#pragma unroll
    for (int rep = 0; rep < 16; ++rep) {
      const int i = rep * 4 + (tid >> 6), j = tid & 63;
      T[i][j] = s[(long)(m0 + i) * N + n0 + j];
    }
  } else {
    const __bf16* s = (const __bf16*)src;
#pragma unroll
    for (int rep = 0; rep < 16; ++rep) {
      const int i = rep * 4 + (tid >> 6), j = tid & 63;
      T[i][j] = (float)s[(long)(m0 + i) * N + n0 + j];
    }
  }
  __syncthreads();
#pragma unroll
  for (int rep = 0; rep < 16; ++rep) {
    const int i = rep * 4 + (tid >> 6), j = tid & 63;
    dst[(long)(n0 + i) * M + m0 + j] = (__bf16)T[j][i];
  }
}

// ---------------------------------------------------------------------------
// K1: qkv = hb @ w_qkv via MFMA (pure bf16). Bt = w_qkv^T. Tile 64x64, K-chunk 128.
// LDS rows padded to 136 bf16 (272 B) -> conflict-light b128 access.
// ---------------------------------------------------------------------------
__global__ __launch_bounds__(256) void gemm_h_wqkv(const __bf16* __restrict__ A,
                                                   const __bf16* __restrict__ Bt,
                                                   __bf16* __restrict__ C) {
  __shared__ __bf16 At[64][136];
  __shared__ __bf16 Bts[64][136];
  const int n0 = blockIdx.x * 64, m0 = blockIdx.y * 64;
  const int tid = threadIdx.x, lane = tid & 63, wv = tid >> 6;
  const int m = lane & 15, q = lane >> 4;
  f32x4 acc[4];
#pragma unroll
  for (int i = 0; i < 4; ++i) acc[i] = f32x4{0.f, 0.f, 0.f, 0.f};

  for (int k0 = 0; k0 < DM; k0 += 128) {
    __syncthreads();
    {
      const int r = tid >> 2, c0 = (tid & 3) * 32;
      const __bf16* ap = A + (long)(m0 + r) * DM + k0 + c0;
      const __bf16* bp = Bt + (long)(n0 + r) * DM + k0 + c0;
#pragma unroll
      for (int j4 = 0; j4 < 4; ++j4) {
        *reinterpret_cast<bf16x8*>(&At[r][c0 + j4 * 8]) =
            *reinterpret_cast<const bf16x8*>(ap + j4 * 8);
        *reinterpret_cast<bf16x8*>(&Bts[r][c0 + j4 * 8]) =
            *reinterpret_cast<const bf16x8*>(bp + j4 * 8);
      }
    }
    __syncthreads();
#pragma unroll
    for (int kk = 0; kk < 4; ++kk) {
      const bf16x8 af = *reinterpret_cast<const bf16x8*>(&At[wv * 16 + m][kk * 32 + q * 8]);
#pragma unroll
      for (int c = 0; c < 4; ++c) {
        const bf16x8 bf = *reinterpret_cast<const bf16x8*>(&Bts[c * 16 + m][kk * 32 + q * 8]);
        acc[c] = MFMA16(af, bf, acc[c]);
      }
    }
  }
#pragma unroll
  for (int r = 0; r < 4; ++r)
#pragma unroll
    for (int c = 0; c < 4; ++c)
      C[(long)(m0 + wv * 16 + q * 4 + r) * QKVN + n0 + c * 16 + m] = (__bf16)acc[c][r];
}

// ---------------------------------------------------------------------------
// K2: Performer features, pure bf16. norm(prime(x,P)) == softmax([xP,-xP]).
// ---------------------------------------------------------------------------
__global__ void features(const __bf16* __restrict__ qkv, const __bf16* __restrict__ proj,
                         const __bf16* __restrict__ pi0, const __bf16* __restrict__ pi1,
                         int bh0, __bf16* __restrict__ qf, __bf16* __restrict__ kf) {
  const int idx = blockIdx.x;
  const int l = idx & 255;
  const int bhl = idx >> 8;
  const int bhg = bhl + bh0;
  const int h = bhg & 7, b = bhg >> 3;
  const int tid = threadIdx.x;
  __shared__ float xq[DH], xk1[DH], xk2[DH];
  __shared__ float red[256];

  const long rowbase = (long)(l * B_SZ + b) * QKVN + h * 256;
  if (tid < DH) {
    const float s = 0.35355339059327373f;   // 64^-0.25
    xq[tid]  = (float)qkv[rowbase + tid] * s;
    xk1[tid] = (float)qkv[rowbase + 64 + tid] * s;
    xk2[tid] = (float)qkv[rowbase + 128 + tid] * s;
  }
  __syncthreads();

  float xpq = 0.f, xp1 = 0.f, xp2 = 0.f;
  for (int dd = 0; dd < DH; ++dd) {
    const float p = (float)proj[dd * PM + tid];
    xpq += xq[dd] * p; xp1 += xk1[dd] * p; xp2 += xk2[dd] * p;
  }
  xp2 *= 0.7f;   // SCALE_W

  auto bmax = [&](float v) -> float {
    red[tid] = v; __syncthreads();
    for (int s = 128; s > 0; s >>= 1) { if (tid < s) red[tid] = fmaxf(red[tid], red[tid + s]); __syncthreads(); }
    const float r = red[0]; __syncthreads(); return r;
  };
  auto bsum = [&](float v) -> float {
    red[tid] = v; __syncthreads();
    for (int s = 128; s > 0; s >>= 1) { if (tid < s) red[tid] += red[tid + s]; __syncthreads(); }
    const float r = red[0]; __syncthreads(); return r;
  };

  const long obase = (long)idx * FD;
  {
    const float mx = bmax(fabsf(xpq));
    const float e1 = __expf(xpq - mx), e2 = __expf(-xpq - mx);
    const float inv = 1.f / bsum(e1 + e2);
    qf[obase + tid]       = (__bf16)(e1 * inv);
    qf[obase + 256 + tid] = (__bf16)(e2 * inv);
  }
  {
    const float p0 = (float)pi0[h * 256 + l];
    const float p1 = (float)pi1[h * 256 + l];
    const float mx1 = bmax(fabsf(xp1));
    const float a1 = __expf(xp1 - mx1), a2 = __expf(-xp1 - mx1);
    const float i1 = 1.f / bsum(a1 + a2);
    const float mx2 = bmax(fabsf(xp2));
    const float b1 = __expf(xp2 - mx2), b2v = __expf(-xp2 - mx2);
    const float i2 = 1.f / bsum(b1 + b2v);
    kf[obase + tid]       = (__bf16)(p0 * a1 * i1 + p1 * b1 * i2);
    kf[obase + 256 + tid] = (__bf16)(p0 * a2 * i1 + p1 * b2v * i2);
  }
}

// ---------------------------------------------------------------------------
// K2b: pack V transposed per head: vt[bh][d][s] (bf16).
// ---------------------------------------------------------------------------
__global__ __launch_bounds__(256) void vpack(const __bf16* __restrict__ qkv,
                                             __bf16* __restrict__ vt) {
  const int s0 = blockIdx.x * 64;
  const int bh = blockIdx.y;
  const int h = bh & 7, b = bh >> 3;
  __shared__ __bf16 T[64][72];
  const int tid = threadIdx.x;
  {
    const int s = tid >> 2, d0 = (tid & 3) * 16;
    const __bf16* vp = qkv + ((long)((s0 + s) * B_SZ + b)) * QKVN + h * 256 + 192 + d0;
#pragma unroll
    for (int j = 0; j < 16; ++j) T[d0 + j][s] = vp[j];
  }
  __syncthreads();
  {
    const int d = tid >> 2, sc = (tid & 3) * 16;
    __bf16* op = vt + ((long)bh * 64 + d) * 256 + s0 + sc;
    *reinterpret_cast<bf16x8*>(op)     = *reinterpret_cast<const bf16x8*>(&T[d][sc]);
    *reinterpret_cast<bf16x8*>(op + 8) = *reinterpret_cast<const bf16x8*>(&T[d][sc + 8]);
  }
}

// ---------------------------------------------------------------------------
// K3: MFMA flash causal linear attention (validated round 3). 64-row Q-tile,
// Q frags in registers, P via LDS (C->A layout), ones-column denominator.
// ---------------------------------------------------------------------------
__global__ __launch_bounds__(256) void flash_mfma(const __bf16* __restrict__ qf,
                                                  const __bf16* __restrict__ kf,
                                                  const __bf16* __restrict__ vt,
                                                  int bh0,
                                                  __bf16* __restrict__ att) {
  const int t0 = blockIdx.x * 64;
  const int bhl = blockIdx.y;
  const int bhg = bhl + bh0;
  const int h = bhg & 7, b = bhg >> 3;
  const int tid = threadIdx.x, lane = tid & 63, wv = tid >> 6;
  const int m = lane & 15, q = lane >> 4;
  __shared__ __bf16 Kc[64][136];
  __shared__ __bf16 Vt[80][72];
  __shared__ __bf16 Pt[64][72];

  bf16x8 qreg[16];
  {
    const __bf16* qp = qf + ((long)(bhl * 256 + t0 + wv * 16 + m)) * FD + q * 8;
#pragma unroll
    for (int ks = 0; ks < 16; ++ks)
      qreg[ks] = *reinterpret_cast<const bf16x8*>(qp + ks * 32);
  }
  f32x4 oacc[5];
#pragma unroll
  for (int i = 0; i < 5; ++i) oacc[i] = f32x4{0.f, 0.f, 0.f, 0.f};

  const int nst = (t0 >> 6) + 1;
  for (int st = 0; st < nst; ++st) {
    const int s0 = st * 64;
    f32x4 sacc[4];
#pragma unroll
    for (int i = 0; i < 4; ++i) sacc[i] = f32x4{0.f, 0.f, 0.f, 0.f};
    __syncthreads();
    {
      const int d = tid >> 2, sc = (tid & 3) * 16;
      const __bf16* vp = vt + ((long)bhg * 64 + d) * 256 + s0 + sc;
      *reinterpret_cast<bf16x8*>(&Vt[d][sc])     = *reinterpret_cast<const bf16x8*>(vp);
      *reinterpret_cast<bf16x8*>(&Vt[d][sc + 8]) = *reinterpret_cast<const bf16x8*>(vp + 8);
      if (tid < 64) Vt[64][tid] = (__bf16)1.0f;
      if (st == 0)
        for (int z = tid; z < 15 * 64; z += 256) Vt[65 + (z >> 6)][z & 63] = (__bf16)0.f;
    }
    for (int ch = 0; ch < 4; ++ch) {
      if (ch) __syncthreads();
      {
        const int r = tid >> 2, c0 = (tid & 3) * 32;
        const __bf16* kp = kf + ((long)(bhl * 256 + s0 + r)) * FD + ch * 128 + c0;
#pragma unroll
        for (int j = 0; j < 4; ++j)
          *reinterpret_cast<bf16x8*>(&Kc[r][c0 + j * 8]) =
              *reinterpret_cast<const bf16x8*>(kp + j * 8);
      }
      __syncthreads();
#pragma unroll
      for (int kk = 0; kk < 4; ++kk) {
        const bf16x8 af = qreg[ch * 4 + kk];
#pragma unroll
        for (int c = 0; c < 4; ++c) {
          const bf16x8 bf = *reinterpret_cast<const bf16x8*>(&Kc[c * 16 + m][kk * 32 + q * 8]);
          sacc[c] = MFMA16(af, bf, sacc[c]);
        }
      }
    }
#pragma unroll
    for (int c = 0; c < 4; ++c)
#pragma unroll
      for (int r = 0; r < 4; ++r) {
        const int row = wv * 16 + q * 4 + r, col = c * 16 + m;
        Pt[row][col] = (__bf16)(((s0 + col) <= (t0 + row)) ? sacc[c][r] : 0.f);
      }
#pragma unroll
    for (int kk = 0; kk < 2; ++kk) {
      const bf16x8 pf = *reinterpret_cast<const bf16x8*>(&Pt[wv * 16 + m][kk * 32 + q * 8]);
#pragma unroll
      for (int c = 0; c < 5; ++c) {
        const bf16x8 vf = *reinterpret_cast<const bf16x8*>(&Vt[c * 16 + m][kk * 32 + q * 8]);
        oacc[c] = MFMA16(pf, vf, oacc[c]);
      }
    }
  }
#pragma unroll
  for (int r = 0; r < 4; ++r) {
    const float den = __shfl(oacc[4][r], (lane & 48));
    const float inv = 0.125f / (den + 1e-5f);           // SCALE=64^-0.5, EPS
    const int row = t0 + wv * 16 + q * 4 + r;
#pragma unroll
    for (int c = 0; c < 4; ++c)
      att[((long)(row * B_SZ + b)) * DM + h * DH + c * 16 + m] = (__bf16)(oacc[c][r] * inv);
  }
}

// ---------------------------------------------------------------------------
// K4: xrow = hb + att @ w_o (f32 out), MFMA, Bt = w_o^T, pure bf16 inputs.
// ---------------------------------------------------------------------------
__global__ __launch_bounds__(256) void gemm_att_wo(const __bf16* __restrict__ A,
                                                   const __bf16* __restrict__ Bt,
                                                   const __bf16* __restrict__ hb,
                                                   float* __restrict__ xrow) {
  __shared__ __bf16 At[64][136];
  __shared__ __bf16 Bts[64][136];
  const int n0 = blockIdx.x * 64, m0 = blockIdx.y * 64;
  const int tid = threadIdx.x, lane = tid & 63, wv = tid >> 6;
  const int m = lane & 15, q = lane >> 4;
  f32x4 acc[4];
#pragma unroll
  for (int i = 0; i < 4; ++i) acc[i] = f32x4{0.f, 0.f, 0.f, 0.f};

  for (int k0 = 0; k0 < DM; k0 += 128) {
    __syncthreads();
    {
      const int r = tid >> 2, c0 = (tid & 3) * 32;
      const __bf16* ap = A + (long)(m0 + r) * DM + k0 + c0;
      const __bf16* bp = Bt + (long)(n0 + r) * DM + k0 + c0;
#pragma unroll
      for (int j4 = 0; j4 < 4; ++j4) {
        *reinterpret_cast<bf16x8*>(&At[r][c0 + j4 * 8]) =
            *reinterpret_cast<const bf16x8*>(ap + j4 * 8);
        *reinterpret_cast<bf16x8*>(&Bts[r][c0 + j4 * 8]) =
            *reinterpret_cast<const bf16x8*>(bp + j4 * 8);
      }
    }
    __syncthreads();
#pragma unroll
    for (int kk = 0; kk < 4; ++kk) {
      const bf16x8 af = *reinterpret_cast<const bf16x8*>(&At[wv * 16 + m][kk * 32 + q * 8]);
#pragma unroll
      for (int c = 0; c < 4; ++c) {
        const bf16x8 bf = *reinterpret_cast<const bf16x8*>(&Bts[c * 16 + m][kk * 32 + q * 8]);
        acc[c] = MFMA16(af, bf, acc[c]);
      }
    }
  }
#pragma unroll
  for (int r = 0; r < 4; ++r)
#pragma unroll
    for (int c = 0; c < 4; ++c) {
      const long row = m0 + wv * 16 + q * 4 + r;
      const long col = n0 + c * 16 + m;
      xrow[row * DM + col] = acc[c][r] + (float)hb[row * DM + col];
    }
}

// ---------------------------------------------------------------------------
// K5: LayerNorm rows of xrow -> out (dtype per flag). One block per row.
// ---------------------------------------------------------------------------
__global__ __launch_bounds__(256) void ln_out(const float* __restrict__ xrow,
                                              const __bf16* __restrict__ gamma,
                                              const __bf16* __restrict__ beta,
                                              const int* __restrict__ flag,
                                              void* __restrict__ out) {
  const int f32 = flag[0];
  const int r = blockIdx.x;
  const int tid = threadIdx.x;
  __shared__ float red[256];
  const float x0 = xrow[(long)r * DM + tid];
  const float x1 = xrow[(long)r * DM + tid + 256];

  red[tid] = x0 + x1; __syncthreads();
  for (int s = 128; s > 0; s >>= 1) { if (tid < s) red[tid] += red[tid + s]; __syncthreads(); }
  const float mu = red[0] * (1.f / 512.f); __syncthreads();
  red[tid] = x0 * x0 + x1 * x1; __syncthreads();
  for (int s = 128; s > 0; s >>= 1) { if (tid < s) red[tid] += red[tid + s]; __syncthreads(); }
  const float var = red[0] * (1.f / 512.f) - mu * mu; __syncthreads();
  const float rstd = rsqrtf(var + 1e-5f);

  stmix(out, (long)r * DM + tid,
        (x0 - mu) * rstd * (float)gamma[tid] + (float)beta[tid], f32);
  stmix(out, (long)r * DM + tid + 256,
        (x1 - mu) * rstd * (float)gamma[tid + 256] + (float)beta[tid + 256], f32);
}

// ---------------------------------------------------------------------------
extern "C" void kernel_launch(void* const* d_in, const int* in_sizes, int n_in,
                              void* d_out, int out_size, void* d_ws, size_t ws_size,
                              hipStream_t stream) {
  (void)in_sizes; (void)n_in; (void)out_size;
  // Workspace layout (bytes):
  //   qkv   bf16 [8192,2048]   @ 0           33,554,432
  //   flag  int                @ 33,554,432  256
  //   wt    bf16 [2048,512]    @ 33,554,688  2,097,152   (w_qkv^T)
  //   wot   bf16 [512,512]     @ 35,651,840  524,288     (w_o^T)
  //   att   bf16 [8192,512]    @ 36,176,128  8,388,608
  //   vt    bf16 [256,64,256]  @ 44,564,736  8,388,608
  //   hb    bf16 [8192,512]    @ 52,953,344  8,388,608
  //   projb bf16 [64,256]      @ 61,341,952  32,768
  //   pi0b  bf16 [8,256]       @ 61,374,720  4,096
  //   pi1b  bf16 [8,256]       @ 61,378,816  4,096
  //   gamb  bf16 [512]         @ 61,382,912  1,024
  //   betb  bf16 [512]         @ 61,383,936  1,024
  //   R (qf/kf groups; xrow f32 16.8MB aliases after flash)  @ 61,384,960
  char* ws = (char*)d_ws;
  __bf16* qkv   = (__bf16*)ws;
  int*    flag  = (int*)(ws + 33554432);
  __bf16* wt    = (__bf16*)(ws + 33554688);
  __bf16* wot   = (__bf16*)(ws + 35651840);
  __bf16* att   = (__bf16*)(ws + 36176128);
  __bf16* vt    = (__bf16*)(ws + 44564736);
  __bf16* hb    = (__bf16*)(ws + 52953344);
  __bf16* projb = (__bf16*)(ws + 61341952);
  __bf16* pi0b  = (__bf16*)(ws + 61374720);
  __bf16* pi1b  = (__bf16*)(ws + 61378816);
  __bf16* gamb  = (__bf16*)(ws + 61382912);
  __bf16* betb  = (__bf16*)(ws + 61383936);
  char*   R     = ws + 61384960;
  float*  xrow  = (float*)R;           // aliases qf/kf (used after flash done)

  const unsigned long long base = 61384960ull;
  int G = 32;
  for (int g : {1, 2, 4, 8, 16, 32}) {
    unsigned long long need = 2ull * (67108864ull / (unsigned)g);
    if (need < 16777216ull) need = 16777216ull;
    if (base + need <= (unsigned long long)ws_size) { G = g; break; }
  }
  __bf16* qf = (__bf16*)R;
  __bf16* kf = qf + (33554432L / G);

  probe_dtype<<<1, 256, 0, stream>>>((const unsigned short*)d_in[0], flag);
  cvt_bf16<<<2048, 256, 0, stream>>>(d_in[0], hb, flag, ROWS * DM / 8);        // h
  cvt_bf16<<<8, 256, 0, stream>>>(d_in[7], projb, flag, DH * PM / 8);          // proj
  cvt_bf16<<<1, 256, 0, stream>>>(d_in[5], pi0b, flag, NH * 256 / 8);          // pi0
  cvt_bf16<<<1, 256, 0, stream>>>(d_in[6], pi1b, flag, NH * 256 / 8);          // pi1
  cvt_bf16<<<1, 256, 0, stream>>>(d_in[3], gamb, flag, DM / 8);                // gamma
  cvt_bf16<<<1, 256, 0, stream>>>(d_in[4], betb, flag, DM / 8);                // beta
  transpose_bf<<<dim3(32, 8), 256, 0, stream>>>(d_in[1], flag, wt, 512, 2048); // w_qkv^T
  transpose_bf<<<dim3(8, 8), 256, 0, stream>>>(d_in[2], flag, wot, 512, 512);  // w_o^T

  gemm_h_wqkv<<<dim3(32, 128), 256, 0, stream>>>(hb, wt, qkv);
  vpack<<<dim3(4, 256), 256, 0, stream>>>(qkv, vt);

  const int nbh = 256 / G;
  for (int g = 0; g < G; ++g) {
    features<<<dim3(nbh * 256), 256, 0, stream>>>(qkv, projb, pi0b, pi1b, g * nbh, qf, kf);
    flash_mfma<<<dim3(4, nbh), 256, 0, stream>>>(qf, kf, vt, g * nbh, att);
  }
  gemm_att_wo<<<dim3(8, 128), 256, 0, stream>>>(att, wot, hb, xrow);
  ln_out<<<dim3(ROWS), 256, 0, stream>>>(xrow, gamb, betb, flag, d_out);
}

// Round 5
// 305.761 us; speedup vs baseline: 6.4229x; 6.4229x over previous
//
#include <hip/hip_runtime.h>
#include <hip/hip_bf16.h>

// L=256, B=32, H=8, d_head=64, m=256, feature dim 2m=512, D_MODEL=512
#define L_SEQ 256
#define B_SZ  32
#define NH    8
#define DH    64
#define DM    512
#define FD    512
#define PM    256
#define ROWS  8192
#define QKVN  2048

typedef __bf16 bf16x8 __attribute__((ext_vector_type(8)));
typedef float f32x4 __attribute__((ext_vector_type(4)));
#define MFMA16(a, b, c) __builtin_amdgcn_mfma_f32_16x16x32_bf16((a), (b), (c), 0, 0, 0)

static __device__ __forceinline__ void stmix(void* p, long i, float v, int f32) {
  if (f32) ((float*)p)[i] = v;
  else     ((__bf16*)p)[i] = (__bf16)v;
}

// ---------------------------------------------------------------------------
// P0: dtype probe (validated rounds 2-4). bf16 N(0,1): no exponent >= 0xA0;
// f32-as-u16 odd halves: ~37% land there.
// ---------------------------------------------------------------------------
__global__ void probe_dtype(const unsigned short* __restrict__ hbits, int* __restrict__ flag) {
  __shared__ int red[256];
  const int tid = threadIdx.x;
  int cnt = 0;
  for (int i = 0; i < 16; ++i) {
    const unsigned short u = hbits[tid * 16 + i];
    const int e = (u >> 7) & 0xFF;
    if (e >= 0xA0) ++cnt;
  }
  red[tid] = cnt; __syncthreads();
  for (int s = 128; s > 0; s >>= 1) { if (tid < s) red[tid] += red[tid + s]; __syncthreads(); }
  if (tid == 0) flag[0] = (red[0] >= 64) ? 1 : 0;
}

// ---------------------------------------------------------------------------
// C0: bf16 conversion, dtype branch hoisted, vectorized (validated round 4).
// ---------------------------------------------------------------------------
__global__ __launch_bounds__(256) void cvt_bf16(const void* __restrict__ src,
                                                __bf16* __restrict__ dst,
                                                const int* __restrict__ flag, int n8) {
  const int i = blockIdx.x * 256 + threadIdx.x;
  if (i >= n8) return;
  if (flag[0]) {
    const f32x4* s = (const f32x4*)src;
    const f32x4 a = s[i * 2], b = s[i * 2 + 1];
    bf16x8 t;
    t[0] = (__bf16)a[0]; t[1] = (__bf16)a[1]; t[2] = (__bf16)a[2]; t[3] = (__bf16)a[3];
    t[4] = (__bf16)b[0]; t[5] = (__bf16)b[1]; t[6] = (__bf16)b[2]; t[7] = (__bf16)b[3];
    *reinterpret_cast<bf16x8*>(dst + (long)i * 8) = t;
  } else {
    *reinterpret_cast<bf16x8*>(dst + (long)i * 8) = ((const bf16x8*)src)[i];
  }
}

// ---------------------------------------------------------------------------
// T0: dst[n][m] = src[m][n] as bf16 (validated round 4).
// ---------------------------------------------------------------------------
__global__ __launch_bounds__(256) void transpose_bf(const void* __restrict__ src,
                                                    const int* __restrict__ flag,
                                                    __bf16* __restrict__ dst, int M, int N) {
  __shared__ float T[64][69];
  const int n0 = blockIdx.x * 64, m0 = blockIdx.y * 64;
  const int tid = threadIdx.x;
  if (flag[0]) {
    const float* s = (const float*)src;
#pragma unroll
    for (int rep = 0; rep < 16; ++rep) {
      const int i = rep * 4 + (tid >> 6), j = tid & 63;
      T[i][j] = s[(long)(m0 + i) * N + n0 + j];
    }
  } else {
    const __bf16* s = (const __bf16*)src;
#pragma unroll
    for (int rep = 0; rep < 16; ++rep) {
      const int i = rep * 4 + (tid >> 6), j = tid & 63;
      T[i][j] = (float)s[(long)(m0 + i) * N + n0 + j];
    }
  }
  __syncthreads();
#pragma unroll
  for (int rep = 0; rep < 16; ++rep) {
    const int i = rep * 4 + (tid >> 6), j = tid & 63;
    dst[(long)(n0 + i) * M + m0 + j] = (__bf16)T[j][i];
  }
}

// ---------------------------------------------------------------------------
// K1: qkv = hb @ w_qkv via MFMA (validated round 4, ~fast now).
// ---------------------------------------------------------------------------
__global__ __launch_bounds__(256) void gemm_h_wqkv(const __bf16* __restrict__ A,
                                                   const __bf16* __restrict__ Bt,
                                                   __bf16* __restrict__ C) {
  __shared__ __bf16 At[64][136];
  __shared__ __bf16 Bts[64][136];
  const int n0 = blockIdx.x * 64, m0 = blockIdx.y * 64;
  const int tid = threadIdx.x, lane = tid & 63, wv = tid >> 6;
  const int m = lane & 15, q = lane >> 4;
  f32x4 acc[4];
#pragma unroll
  for (int i = 0; i < 4; ++i) acc[i] = f32x4{0.f, 0.f, 0.f, 0.f};

  for (int k0 = 0; k0 < DM; k0 += 128) {
    __syncthreads();
    {
      const int r = tid >> 2, c0 = (tid & 3) * 32;
      const __bf16* ap = A + (long)(m0 + r) * DM + k0 + c0;
      const __bf16* bp = Bt + (long)(n0 + r) * DM + k0 + c0;
#pragma unroll
      for (int j4 = 0; j4 < 4; ++j4) {
        *reinterpret_cast<bf16x8*>(&At[r][c0 + j4 * 8]) =
            *reinterpret_cast<const bf16x8*>(ap + j4 * 8);
        *reinterpret_cast<bf16x8*>(&Bts[r][c0 + j4 * 8]) =
            *reinterpret_cast<const bf16x8*>(bp + j4 * 8);
      }
    }
    __syncthreads();
#pragma unroll
    for (int kk = 0; kk < 4; ++kk) {
      const bf16x8 af = *reinterpret_cast<const bf16x8*>(&At[wv * 16 + m][kk * 32 + q * 8]);
#pragma unroll
      for (int c = 0; c < 4; ++c) {
        const bf16x8 bf = *reinterpret_cast<const bf16x8*>(&Bts[c * 16 + m][kk * 32 + q * 8]);
        acc[c] = MFMA16(af, bf, acc[c]);
      }
    }
  }
#pragma unroll
  for (int r = 0; r < 4; ++r)
#pragma unroll
    for (int c = 0; c < 4; ++c)
      C[(long)(m0 + wv * 16 + q * 4 + r) * QKVN + n0 + c * 16 + m] = (__bf16)acc[c][r];
}

// ---------------------------------------------------------------------------
// K2: Performer features as MFMA GEMM + in-register softmax.
// Block = 64 l-rows x (one bh). projT [256][64] staged ONCE in LDS (the round-4
// pathology was 65536 blocks re-reading proj from HBM: 2.4 GB FETCH).
// norm(prime(x,P)) == softmax([xP,-xP]) (row constants cancel).
// Phases: q -> qf; k2 -> kf = p1*f2; k1 -> kf += p0*f1 (same-lane RMW).
// Softmax reductions: 16-lane __shfl_xor (rows live in 16-lane groups).
// ---------------------------------------------------------------------------
__global__ __launch_bounds__(256) void features_mfma(const __bf16* __restrict__ qkv,
                                                     const __bf16* __restrict__ projT,
                                                     const __bf16* __restrict__ pi0,
                                                     const __bf16* __restrict__ pi1,
                                                     int bh0,
                                                     __bf16* __restrict__ qf,
                                                     __bf16* __restrict__ kf) {
  const int l0 = blockIdx.x * 64;
  const int bhl = blockIdx.y;
  const int bhg = bhl + bh0;
  const int h = bhg & 7, b = bhg >> 3;
  const int tid = threadIdx.x, lane = tid & 63, wv = tid >> 6;
  const int m = lane & 15, q = lane >> 4;
  __shared__ __bf16 Bs[256][72];   // projT rows (n=proj col, k=d), 144 B stride
  __shared__ __bf16 As[64][72];    // current mat tile: 64 l-rows x 64 d

  {
    const __bf16* p = projT + (long)tid * 64;
#pragma unroll
    for (int j = 0; j < 8; ++j)
      *reinterpret_cast<bf16x8*>(&Bs[tid][j * 8]) = *reinterpret_cast<const bf16x8*>(p + j * 8);
  }
  float p0w[4], p1w[4];
#pragma unroll
  for (int r = 0; r < 4; ++r) {
    const int l = l0 + wv * 16 + q * 4 + r;
    p0w[r] = (float)pi0[h * 256 + l];
    p1w[r] = (float)pi1[h * 256 + l];
  }

#pragma unroll
  for (int phase = 0; phase < 3; ++phase) {
    const int moff = (phase == 0) ? 0 : (phase == 1 ? 128 : 64);   // q, k2, k1
    const float scl = (phase == 1) ? 0.24748737f : 0.35355339f;    // 64^-0.25 (*0.7 for k2)
    __syncthreads();   // Bs ready (ph0) / As free to overwrite (ph1,2)
    {
      const int r = tid >> 2, c0 = (tid & 3) * 16;
      const __bf16* ap = qkv + (long)((l0 + r) * B_SZ + b) * QKVN + h * 256 + moff + c0;
      *reinterpret_cast<bf16x8*>(&As[r][c0])     = *reinterpret_cast<const bf16x8*>(ap);
      *reinterpret_cast<bf16x8*>(&As[r][c0 + 8]) = *reinterpret_cast<const bf16x8*>(ap + 8);
    }
    __syncthreads();

    f32x4 acc[16];
#pragma unroll
    for (int c = 0; c < 16; ++c) acc[c] = f32x4{0.f, 0.f, 0.f, 0.f};
#pragma unroll
    for (int kk = 0; kk < 2; ++kk) {
      const bf16x8 af = *reinterpret_cast<const bf16x8*>(&As[wv * 16 + m][kk * 32 + q * 8]);
#pragma unroll
      for (int c = 0; c < 16; ++c) {
        const bf16x8 bf = *reinterpret_cast<const bf16x8*>(&Bs[c * 16 + m][kk * 32 + q * 8]);
        acc[c] = MFMA16(af, bf, acc[c]);
      }
    }

    float mx[4] = {0.f, 0.f, 0.f, 0.f}, sm[4] = {0.f, 0.f, 0.f, 0.f};
#pragma unroll
    for (int c = 0; c < 16; ++c)
#pragma unroll
      for (int r = 0; r < 4; ++r) mx[r] = fmaxf(mx[r], fabsf(acc[c][r] * scl));
#pragma unroll
    for (int msk = 1; msk < 16; msk <<= 1)
#pragma unroll
      for (int r = 0; r < 4; ++r) mx[r] = fmaxf(mx[r], __shfl_xor(mx[r], msk));
#pragma unroll
    for (int c = 0; c < 16; ++c)
#pragma unroll
      for (int r = 0; r < 4; ++r) {
        const float v = acc[c][r] * scl;
        sm[r] += __expf(v - mx[r]) + __expf(-v - mx[r]);
      }
#pragma unroll
    for (int msk = 1; msk < 16; msk <<= 1)
#pragma unroll
      for (int r = 0; r < 4; ++r) sm[r] += __shfl_xor(sm[r], msk);

    const long base = ((long)bhl * 256 + l0 + wv * 16 + q * 4) * FD;
#pragma unroll
    for (int r = 0; r < 4; ++r) {
      const float inv = 1.f / sm[r];
      const long rb = base + (long)r * FD;
#pragma unroll
      for (int c = 0; c < 16; ++c) {
        const float v = acc[c][r] * scl;
        const float e1 = __expf(v - mx[r]) * inv;
        const float e2 = __expf(-v - mx[r]) * inv;
        const int col = c * 16 + m;
        if (phase == 0) {
          qf[rb + col]       = (__bf16)e1;
          qf[rb + 256 + col] = (__bf16)e2;
        } else if (phase == 1) {
          kf[rb + col]       = (__bf16)(p1w[r] * e1);
          kf[rb + 256 + col] = (__bf16)(p1w[r] * e2);
        } else {
          kf[rb + col]       = (__bf16)((float)kf[rb + col] + p0w[r] * e1);
          kf[rb + 256 + col] = (__bf16)((float)kf[rb + 256 + col] + p0w[r] * e2);
        }
      }
    }
  }
}

// ---------------------------------------------------------------------------
// K2b: pack V transposed per head: vt[bh][d][s] (validated).
// ---------------------------------------------------------------------------
__global__ __launch_bounds__(256) void vpack(const __bf16* __restrict__ qkv,
                                             __bf16* __restrict__ vt) {
  const int s0 = blockIdx.x * 64;
  const int bh = blockIdx.y;
  const int h = bh & 7, b = bh >> 3;
  __shared__ __bf16 T[64][72];
  const int tid = threadIdx.x;
  {
    const int s = tid >> 2, d0 = (tid & 3) * 16;
    const __bf16* vp = qkv + ((long)((s0 + s) * B_SZ + b)) * QKVN + h * 256 + 192 + d0;
#pragma unroll
    for (int j = 0; j < 16; ++j) T[d0 + j][s] = vp[j];
  }
  __syncthreads();
  {
    const int d = tid >> 2, sc = (tid & 3) * 16;
    __bf16* op = vt + ((long)bh * 64 + d) * 256 + s0 + sc;
    *reinterpret_cast<bf16x8*>(op)     = *reinterpret_cast<const bf16x8*>(&T[d][sc]);
    *reinterpret_cast<bf16x8*>(op + 8) = *reinterpret_cast<const bf16x8*>(&T[d][sc + 8]);
  }
}

// ---------------------------------------------------------------------------
// K3: MFMA flash causal linear attention (validated round 3/4).
// ---------------------------------------------------------------------------
__global__ __launch_bounds__(256) void flash_mfma(const __bf16* __restrict__ qf,
                                                  const __bf16* __restrict__ kf,
                                                  const __bf16* __restrict__ vt,
                                                  int bh0,
                                                  __bf16* __restrict__ att) {
  const int t0 = blockIdx.x * 64;
  const int bhl = blockIdx.y;
  const int bhg = bhl + bh0;
  const int h = bhg & 7, b = bhg >> 3;
  const int tid = threadIdx.x, lane = tid & 63, wv = tid >> 6;
  const int m = lane & 15, q = lane >> 4;
  __shared__ __bf16 Kc[64][136];
  __shared__ __bf16 Vt[80][72];
  __shared__ __bf16 Pt[64][72];

  bf16x8 qreg[16];
  {
    const __bf16* qp = qf + ((long)(bhl * 256 + t0 + wv * 16 + m)) * FD + q * 8;
#pragma unroll
    for (int ks = 0; ks < 16; ++ks)
      qreg[ks] = *reinterpret_cast<const bf16x8*>(qp + ks * 32);
  }
  f32x4 oacc[5];
#pragma unroll
  for (int i = 0; i < 5; ++i) oacc[i] = f32x4{0.f, 0.f, 0.f, 0.f};

  const int nst = (t0 >> 6) + 1;
  for (int st = 0; st < nst; ++st) {
    const int s0 = st * 64;
    f32x4 sacc[4];
#pragma unroll
    for (int i = 0; i < 4; ++i) sacc[i] = f32x4{0.f, 0.f, 0.f, 0.f};
    __syncthreads();
    {
      const int d = tid >> 2, sc = (tid & 3) * 16;
      const __bf16* vp = vt + ((long)bhg * 64 + d) * 256 + s0 + sc;
      *reinterpret_cast<bf16x8*>(&Vt[d][sc])     = *reinterpret_cast<const bf16x8*>(vp);
      *reinterpret_cast<bf16x8*>(&Vt[d][sc + 8]) = *reinterpret_cast<const bf16x8*>(vp + 8);
      if (tid < 64) Vt[64][tid] = (__bf16)1.0f;
      if (st == 0)
        for (int z = tid; z < 15 * 64; z += 256) Vt[65 + (z >> 6)][z & 63] = (__bf16)0.f;
    }
    for (int ch = 0; ch < 4; ++ch) {
      if (ch) __syncthreads();
      {
        const int r = tid >> 2, c0 = (tid & 3) * 32;
        const __bf16* kp = kf + ((long)(bhl * 256 + s0 + r)) * FD + ch * 128 + c0;
#pragma unroll
        for (int j = 0; j < 4; ++j)
          *reinterpret_cast<bf16x8*>(&Kc[r][c0 + j * 8]) =
              *reinterpret_cast<const bf16x8*>(kp + j * 8);
      }
      __syncthreads();
#pragma unroll
      for (int kk = 0; kk < 4; ++kk) {
        const bf16x8 af = qreg[ch * 4 + kk];
#pragma unroll
        for (int c = 0; c < 4; ++c) {
          const bf16x8 bf = *reinterpret_cast<const bf16x8*>(&Kc[c * 16 + m][kk * 32 + q * 8]);
          sacc[c] = MFMA16(af, bf, sacc[c]);
        }
      }
    }
#pragma unroll
    for (int c = 0; c < 4; ++c)
#pragma unroll
      for (int r = 0; r < 4; ++r) {
        const int row = wv * 16 + q * 4 + r, col = c * 16 + m;
        Pt[row][col] = (__bf16)(((s0 + col) <= (t0 + row)) ? sacc[c][r] : 0.f);
      }
#pragma unroll
    for (int kk = 0; kk < 2; ++kk) {
      const bf16x8 pf = *reinterpret_cast<const bf16x8*>(&Pt[wv * 16 + m][kk * 32 + q * 8]);
#pragma unroll
      for (int c = 0; c < 5; ++c) {
        const bf16x8 vf = *reinterpret_cast<const bf16x8*>(&Vt[c * 16 + m][kk * 32 + q * 8]);
        oacc[c] = MFMA16(pf, vf, oacc[c]);
      }
    }
  }
#pragma unroll
  for (int r = 0; r < 4; ++r) {
    const float den = __shfl(oacc[4][r], (lane & 48));
    const float inv = 0.125f / (den + 1e-5f);           // SCALE=64^-0.5, EPS
    const int row = t0 + wv * 16 + q * 4 + r;
#pragma unroll
    for (int c = 0; c < 4; ++c)
      att[((long)(row * B_SZ + b)) * DM + h * DH + c * 16 + m] = (__bf16)(oacc[c][r] * inv);
  }
}

// ---------------------------------------------------------------------------
// K4: xrow = hb + att @ w_o (f32 out), MFMA (validated round 4).
// ---------------------------------------------------------------------------
__global__ __launch_bounds__(256) void gemm_att_wo(const __bf16* __restrict__ A,
                                                   const __bf16* __restrict__ Bt,
                                                   const __bf16* __restrict__ hb,
                                                   float* __restrict__ xrow) {
  __shared__ __bf16 At[64][136];
  __shared__ __bf16 Bts[64][136];
  const int n0 = blockIdx.x * 64, m0 = blockIdx.y * 64;
  const int tid = threadIdx.x, lane = tid & 63, wv = tid >> 6;
  const int m = lane & 15, q = lane >> 4;
  f32x4 acc[4];
#pragma unroll
  for (int i = 0; i < 4; ++i) acc[i] = f32x4{0.f, 0.f, 0.f, 0.f};

  for (int k0 = 0; k0 < DM; k0 += 128) {
    __syncthreads();
    {
      const int r = tid >> 2, c0 = (tid & 3) * 32;
      const __bf16* ap = A + (long)(m0 + r) * DM + k0 + c0;
      const __bf16* bp = Bt + (long)(n0 + r) * DM + k0 + c0;
#pragma unroll
      for (int j4 = 0; j4 < 4; ++j4) {
        *reinterpret_cast<bf16x8*>(&At[r][c0 + j4 * 8]) =
            *reinterpret_cast<const bf16x8*>(ap + j4 * 8);
        *reinterpret_cast<bf16x8*>(&Bts[r][c0 + j4 * 8]) =
            *reinterpret_cast<const bf16x8*>(bp + j4 * 8);
      }
    }
    __syncthreads();
#pragma unroll
    for (int kk = 0; kk < 4; ++kk) {
      const bf16x8 af = *reinterpret_cast<const bf16x8*>(&At[wv * 16 + m][kk * 32 + q * 8]);
#pragma unroll
      for (int c = 0; c < 4; ++c) {
        const bf16x8 bf = *reinterpret_cast<const bf16x8*>(&Bts[c * 16 + m][kk * 32 + q * 8]);
        acc[c] = MFMA16(af, bf, acc[c]);
      }
    }
  }
#pragma unroll
  for (int r = 0; r < 4; ++r)
#pragma unroll
    for (int c = 0; c < 4; ++c) {
      const long row = m0 + wv * 16 + q * 4 + r;
      const long col = n0 + c * 16 + m;
      xrow[row * DM + col] = acc[c][r] + (float)hb[row * DM + col];
    }
}

// ---------------------------------------------------------------------------
// K5: LayerNorm rows of xrow -> out (validated round 4).
// ---------------------------------------------------------------------------
__global__ __launch_bounds__(256) void ln_out(const float* __restrict__ xrow,
                                              const __bf16* __restrict__ gamma,
                                              const __bf16* __restrict__ beta,
                                              const int* __restrict__ flag,
                                              void* __restrict__ out) {
  const int f32 = flag[0];
  const int r = blockIdx.x;
  const int tid = threadIdx.x;
  __shared__ float red[256];
  const float x0 = xrow[(long)r * DM + tid];
  const float x1 = xrow[(long)r * DM + tid + 256];

  red[tid] = x0 + x1; __syncthreads();
  for (int s = 128; s > 0; s >>= 1) { if (tid < s) red[tid] += red[tid + s]; __syncthreads(); }
  const float mu = red[0] * (1.f / 512.f); __syncthreads();
  red[tid] = x0 * x0 + x1 * x1; __syncthreads();
  for (int s = 128; s > 0; s >>= 1) { if (tid < s) red[tid] += red[tid + s]; __syncthreads(); }
  const float var = red[0] * (1.f / 512.f) - mu * mu; __syncthreads();
  const float rstd = rsqrtf(var + 1e-5f);

  stmix(out, (long)r * DM + tid,
        (x0 - mu) * rstd * (float)gamma[tid] + (float)beta[tid], f32);
  stmix(out, (long)r * DM + tid + 256,
        (x1 - mu) * rstd * (float)gamma[tid + 256] + (float)beta[tid + 256], f32);
}

// ---------------------------------------------------------------------------
extern "C" void kernel_launch(void* const* d_in, const int* in_sizes, int n_in,
                              void* d_out, int out_size, void* d_ws, size_t ws_size,
                              hipStream_t stream) {
  (void)in_sizes; (void)n_in; (void)out_size;
  // Workspace layout (bytes):
  //   qkv   bf16 [8192,2048]   @ 0           33,554,432
  //   flag  int                @ 33,554,432  256
  //   wt    bf16 [2048,512]    @ 33,554,688  2,097,152   (w_qkv^T)
  //   wot   bf16 [512,512]     @ 35,651,840  524,288     (w_o^T)
  //   att   bf16 [8192,512]    @ 36,176,128  8,388,608
  //   vt    bf16 [256,64,256]  @ 44,564,736  8,388,608
  //   hb    bf16 [8192,512]    @ 52,953,344  8,388,608
  //   projT bf16 [256,64]      @ 61,341,952  32,768      (proj^T)
  //   pi0b  bf16 [8,256]       @ 61,374,720  4,096
  //   pi1b  bf16 [8,256]       @ 61,378,816  4,096
  //   gamb  bf16 [512]         @ 61,382,912  1,024
  //   betb  bf16 [512]         @ 61,383,936  1,024
  //   R (qf/kf groups; xrow f32 16.8MB aliases after flash)  @ 61,384,960
  char* ws = (char*)d_ws;
  __bf16* qkv   = (__bf16*)ws;
  int*    flag  = (int*)(ws + 33554432);
  __bf16* wt    = (__bf16*)(ws + 33554688);
  __bf16* wot   = (__bf16*)(ws + 35651840);
  __bf16* att   = (__bf16*)(ws + 36176128);
  __bf16* vt    = (__bf16*)(ws + 44564736);
  __bf16* hb    = (__bf16*)(ws + 52953344);
  __bf16* projT = (__bf16*)(ws + 61341952);
  __bf16* pi0b  = (__bf16*)(ws + 61374720);
  __bf16* pi1b  = (__bf16*)(ws + 61378816);
  __bf16* gamb  = (__bf16*)(ws + 61382912);
  __bf16* betb  = (__bf16*)(ws + 61383936);
  char*   R     = ws + 61384960;
  float*  xrow  = (float*)R;           // aliases qf/kf (used after flash done)

  const unsigned long long base = 61384960ull;
  int G = 32;
  for (int g : {1, 2, 4, 8, 16, 32}) {
    unsigned long long need = 2ull * (67108864ull / (unsigned)g);
    if (need < 16777216ull) need = 16777216ull;
    if (base + need <= (unsigned long long)ws_size) { G = g; break; }
  }
  __bf16* qf = (__bf16*)R;
  __bf16* kf = qf + (33554432L / G);

  probe_dtype<<<1, 256, 0, stream>>>((const unsigned short*)d_in[0], flag);
  cvt_bf16<<<2048, 256, 0, stream>>>(d_in[0], hb, flag, ROWS * DM / 8);        // h
  cvt_bf16<<<1, 256, 0, stream>>>(d_in[5], pi0b, flag, NH * 256 / 8);          // pi0
  cvt_bf16<<<1, 256, 0, stream>>>(d_in[6], pi1b, flag, NH * 256 / 8);          // pi1
  cvt_bf16<<<1, 256, 0, stream>>>(d_in[3], gamb, flag, DM / 8);                // gamma
  cvt_bf16<<<1, 256, 0, stream>>>(d_in[4], betb, flag, DM / 8);                // beta
  transpose_bf<<<dim3(32, 8), 256, 0, stream>>>(d_in[1], flag, wt, 512, 2048); // w_qkv^T
  transpose_bf<<<dim3(8, 8), 256, 0, stream>>>(d_in[2], flag, wot, 512, 512);  // w_o^T
  transpose_bf<<<dim3(4, 1), 256, 0, stream>>>(d_in[7], flag, projT, 64, 256); // proj^T

  gemm_h_wqkv<<<dim3(32, 128), 256, 0, stream>>>(hb, wt, qkv);
  vpack<<<dim3(4, 256), 256, 0, stream>>>(qkv, vt);

  const int nbh = 256 / G;
  for (int g = 0; g < G; ++g) {
    features_mfma<<<dim3(4, nbh), 256, 0, stream>>>(qkv, projT, pi0b, pi1b, g * nbh, qf, kf);
    flash_mfma<<<dim3(4, nbh), 256, 0, stream>>>(qf, kf, vt, g * nbh, att);
  }
  gemm_att_wo<<<dim3(8, 128), 256, 0, stream>>>(att, wot, hb, xrow);
  ln_out<<<dim3(ROWS), 256, 0, stream>>>(xrow, gamb, betb, flag, d_out);
}

// Round 6
// 299.645 us; speedup vs baseline: 6.5540x; 1.0204x over previous
//
#include <hip/hip_runtime.h>
#include <hip/hip_bf16.h>

// L=256, B=32, H=8, d_head=64, m=256, feature dim 2m=512, D_MODEL=512
#define L_SEQ 256
#define B_SZ  32
#define NH    8
#define DH    64
#define DM    512
#define FD    512
#define PM    256
#define ROWS  8192
#define QKVN  2048

typedef __bf16 bf16x8 __attribute__((ext_vector_type(8)));
typedef float f32x4 __attribute__((ext_vector_type(4)));
#define MFMA16(a, b, c) __builtin_amdgcn_mfma_f32_16x16x32_bf16((a), (b), (c), 0, 0, 0)

static __device__ __forceinline__ void stmix(void* p, long i, float v, int f32) {
  if (f32) ((float*)p)[i] = v;
  else     ((__bf16*)p)[i] = (__bf16)v;
}

// ---------------------------------------------------------------------------
// P0: small_prep — dtype probe + tiny input conversions, one launch, 5 blocks.
// Each block re-probes h's first 8 KB inline (bf16 N(0,1): no exponent >=
// 0xA0; f32-as-u16 odd halves: ~37% there) so no cross-block flag dependency.
// Block 0 additionally publishes the flag for downstream kernels.
// ---------------------------------------------------------------------------
__global__ __launch_bounds__(256) void small_prep(const unsigned short* __restrict__ hbits,
                                                  const void* __restrict__ pi0,
                                                  const void* __restrict__ pi1,
                                                  const void* __restrict__ gam,
                                                  const void* __restrict__ bet,
                                                  int* __restrict__ flag,
                                                  __bf16* __restrict__ pi0b,
                                                  __bf16* __restrict__ pi1b,
                                                  __bf16* __restrict__ gamb,
                                                  __bf16* __restrict__ betb) {
  __shared__ int red[256];
  const int tid = threadIdx.x;
  int cnt = 0;
  for (int i = 0; i < 16; ++i) {
    const unsigned short u = hbits[tid * 16 + i];
    if (((u >> 7) & 0xFF) >= 0xA0) ++cnt;
  }
  red[tid] = cnt; __syncthreads();
  for (int s = 128; s > 0; s >>= 1) { if (tid < s) red[tid] += red[tid + s]; __syncthreads(); }
  const int f32 = (red[0] >= 64) ? 1 : 0;
  const int blk = blockIdx.x;
  if (blk == 0) {
    if (tid == 0) flag[0] = f32;
    return;
  }
  const void* src = (blk == 1) ? pi0 : (blk == 2) ? pi1 : (blk == 3) ? gam : bet;
  __bf16* dst = (blk == 1) ? pi0b : (blk == 2) ? pi1b : (blk == 3) ? gamb : betb;
  const int n = (blk <= 2) ? NH * 256 : DM;
  if (f32) {
    const float* s = (const float*)src;
    for (int i = tid; i < n; i += 256) dst[i] = (__bf16)s[i];
  } else {
    const __bf16* s = (const __bf16*)src;
    for (int i = tid; i < n; i += 256) dst[i] = s[i];
  }
}

// ---------------------------------------------------------------------------
// C0: bf16 conversion, dtype branch hoisted, vectorized (validated round 4/5).
// ---------------------------------------------------------------------------
__global__ __launch_bounds__(256) void cvt_bf16(const void* __restrict__ src,
                                                __bf16* __restrict__ dst,
                                                const int* __restrict__ flag, int n8) {
  const int i = blockIdx.x * 256 + threadIdx.x;
  if (i >= n8) return;
  if (flag[0]) {
    const f32x4* s = (const f32x4*)src;
    const f32x4 a = s[i * 2], b = s[i * 2 + 1];
    bf16x8 t;
    t[0] = (__bf16)a[0]; t[1] = (__bf16)a[1]; t[2] = (__bf16)a[2]; t[3] = (__bf16)a[3];
    t[4] = (__bf16)b[0]; t[5] = (__bf16)b[1]; t[6] = (__bf16)b[2]; t[7] = (__bf16)b[3];
    *reinterpret_cast<bf16x8*>(dst + (long)i * 8) = t;
  } else {
    *reinterpret_cast<bf16x8*>(dst + (long)i * 8) = ((const bf16x8*)src)[i];
  }
}

// ---------------------------------------------------------------------------
// T0: dst[n][m] = src[m][n] as bf16 (validated round 4/5).
// ---------------------------------------------------------------------------
__global__ __launch_bounds__(256) void transpose_bf(const void* __restrict__ src,
                                                    const int* __restrict__ flag,
                                                    __bf16* __restrict__ dst, int M, int N) {
  __shared__ float T[64][69];
  const int n0 = blockIdx.x * 64, m0 = blockIdx.y * 64;
  const int tid = threadIdx.x;
  if (flag[0]) {
    const float* s = (const float*)src;
#pragma unroll
    for (int rep = 0; rep < 16; ++rep) {
      const int i = rep * 4 + (tid >> 6), j = tid & 63;
      T[i][j] = s[(long)(m0 + i) * N + n0 + j];
    }
  } else {
    const __bf16* s = (const __bf16*)src;
#pragma unroll
    for (int rep = 0; rep < 16; ++rep) {
      const int i = rep * 4 + (tid >> 6), j = tid & 63;
      T[i][j] = (float)s[(long)(m0 + i) * N + n0 + j];
    }
  }
  __syncthreads();
#pragma unroll
  for (int rep = 0; rep < 16; ++rep) {
    const int i = rep * 4 + (tid >> 6), j = tid & 63;
    dst[(long)(n0 + i) * M + m0 + j] = (__bf16)T[j][i];
  }
}

// ---------------------------------------------------------------------------
// K1: qkv = hb @ w_qkv via MFMA (validated round 4/5).
// ---------------------------------------------------------------------------
__global__ __launch_bounds__(256) void gemm_h_wqkv(const __bf16* __restrict__ A,
                                                   const __bf16* __restrict__ Bt,
                                                   __bf16* __restrict__ C) {
  __shared__ __bf16 At[64][136];
  __shared__ __bf16 Bts[64][136];
  const int n0 = blockIdx.x * 64, m0 = blockIdx.y * 64;
  const int tid = threadIdx.x, lane = tid & 63, wv = tid >> 6;
  const int m = lane & 15, q = lane >> 4;
  f32x4 acc[4];
#pragma unroll
  for (int i = 0; i < 4; ++i) acc[i] = f32x4{0.f, 0.f, 0.f, 0.f};

  for (int k0 = 0; k0 < DM; k0 += 128) {
    __syncthreads();
    {
      const int r = tid >> 2, c0 = (tid & 3) * 32;
      const __bf16* ap = A + (long)(m0 + r) * DM + k0 + c0;
      const __bf16* bp = Bt + (long)(n0 + r) * DM + k0 + c0;
#pragma unroll
      for (int j4 = 0; j4 < 4; ++j4) {
        *reinterpret_cast<bf16x8*>(&At[r][c0 + j4 * 8]) =
            *reinterpret_cast<const bf16x8*>(ap + j4 * 8);
        *reinterpret_cast<bf16x8*>(&Bts[r][c0 + j4 * 8]) =
            *reinterpret_cast<const bf16x8*>(bp + j4 * 8);
      }
    }
    __syncthreads();
#pragma unroll
    for (int kk = 0; kk < 4; ++kk) {
      const bf16x8 af = *reinterpret_cast<const bf16x8*>(&At[wv * 16 + m][kk * 32 + q * 8]);
#pragma unroll
      for (int c = 0; c < 4; ++c) {
        const bf16x8 bf = *reinterpret_cast<const bf16x8*>(&Bts[c * 16 + m][kk * 32 + q * 8]);
        acc[c] = MFMA16(af, bf, acc[c]);
      }
    }
  }
#pragma unroll
  for (int r = 0; r < 4; ++r)
#pragma unroll
    for (int c = 0; c < 4; ++c)
      C[(long)(m0 + wv * 16 + q * 4 + r) * QKVN + n0 + c * 16 + m] = (__bf16)acc[c][r];
}

// ---------------------------------------------------------------------------
// K2: Performer features, MFMA + in-register softmax. Round-6 change: k1 and
// k2 computed in ONE phase (two A-tiles, 32 accumulators) and kf written in a
// single pass — kills the round-5 RMW that tripled kf HBM writes (WRITE_SIZE
// 193 MB ~= 3x67 MB: phase-1 lines evicted, re-fetched, re-dirtied).
// norm(prime(x,P)) == softmax([xP,-xP]) (row constants cancel).
// ---------------------------------------------------------------------------
__global__ __launch_bounds__(256) void features_mfma(const __bf16* __restrict__ qkv,
                                                     const __bf16* __restrict__ projT,
                                                     const __bf16* __restrict__ pi0,
                                                     const __bf16* __restrict__ pi1,
                                                     __bf16* __restrict__ qf,
                                                     __bf16* __restrict__ kf) {
  const int l0 = blockIdx.x * 64;
  const int bh = blockIdx.y;
  const int h = bh & 7, b = bh >> 3;
  const int tid = threadIdx.x, lane = tid & 63, wv = tid >> 6;
  const int m = lane & 15, q = lane >> 4;
  __shared__ __bf16 Bs[256][72];     // projT rows (n=proj col, k=d)
  __shared__ __bf16 As[2][64][72];   // A tiles: 64 l-rows x 64 d

  {
    const __bf16* p = projT + (long)tid * 64;
#pragma unroll
    for (int j = 0; j < 8; ++j)
      *reinterpret_cast<bf16x8*>(&Bs[tid][j * 8]) = *reinterpret_cast<const bf16x8*>(p + j * 8);
  }
  float p0w[4], p1w[4];
#pragma unroll
  for (int r = 0; r < 4; ++r) {
    const int l = l0 + wv * 16 + q * 4 + r;
    p0w[r] = (float)pi0[h * 256 + l];
    p1w[r] = (float)pi1[h * 256 + l];
  }
  const float SQ = 0.35355339f;      // 64^-0.25
  const float SK2 = 0.24748737f;     // 0.7 * 64^-0.25

  // ---- phase Q ----
  {
    const int r = tid >> 2, c0 = (tid & 3) * 16;
    const __bf16* ap = qkv + (long)((l0 + r) * B_SZ + b) * QKVN + h * 256 + c0;
    *reinterpret_cast<bf16x8*>(&As[0][r][c0])     = *reinterpret_cast<const bf16x8*>(ap);
    *reinterpret_cast<bf16x8*>(&As[0][r][c0 + 8]) = *reinterpret_cast<const bf16x8*>(ap + 8);
  }
  __syncthreads();
  {
    f32x4 acc[16];
#pragma unroll
    for (int c = 0; c < 16; ++c) acc[c] = f32x4{0.f, 0.f, 0.f, 0.f};
#pragma unroll
    for (int kk = 0; kk < 2; ++kk) {
      const bf16x8 af = *reinterpret_cast<const bf16x8*>(&As[0][wv * 16 + m][kk * 32 + q * 8]);
#pragma unroll
      for (int c = 0; c < 16; ++c) {
        const bf16x8 bf = *reinterpret_cast<const bf16x8*>(&Bs[c * 16 + m][kk * 32 + q * 8]);
        acc[c] = MFMA16(af, bf, acc[c]);
      }
    }
    float mx[4] = {0.f, 0.f, 0.f, 0.f}, sm[4] = {0.f, 0.f, 0.f, 0.f};
#pragma unroll
    for (int c = 0; c < 16; ++c)
#pragma unroll
      for (int r = 0; r < 4; ++r) mx[r] = fmaxf(mx[r], fabsf(acc[c][r] * SQ));
#pragma unroll
    for (int msk = 1; msk < 16; msk <<= 1)
#pragma unroll
      for (int r = 0; r < 4; ++r) mx[r] = fmaxf(mx[r], __shfl_xor(mx[r], msk));
#pragma unroll
    for (int c = 0; c < 16; ++c)
#pragma unroll
      for (int r = 0; r < 4; ++r) {
        const float v = acc[c][r] * SQ;
        sm[r] += __expf(v - mx[r]) + __expf(-v - mx[r]);
      }
#pragma unroll
    for (int msk = 1; msk < 16; msk <<= 1)
#pragma unroll
      for (int r = 0; r < 4; ++r) sm[r] += __shfl_xor(sm[r], msk);

    const long base = ((long)bh * 256 + l0 + wv * 16 + q * 4) * FD;
#pragma unroll
    for (int r = 0; r < 4; ++r) {
      const float inv = 1.f / sm[r];
      const long rb = base + (long)r * FD;
#pragma unroll
      for (int c = 0; c < 16; ++c) {
        const float v = acc[c][r] * SQ;
        const int col = c * 16 + m;
        qf[rb + col]       = (__bf16)(__expf(v - mx[r]) * inv);
        qf[rb + 256 + col] = (__bf16)(__expf(-v - mx[r]) * inv);
      }
    }
  }

  // ---- phase K1+K2 (fused) ----
  __syncthreads();   // all waves done with As[0]
  {
    const int r = tid >> 2, c0 = (tid & 3) * 16;
    const __bf16* a1 = qkv + (long)((l0 + r) * B_SZ + b) * QKVN + h * 256 + 64 + c0;
    const __bf16* a2 = a1 + 64;
    *reinterpret_cast<bf16x8*>(&As[0][r][c0])     = *reinterpret_cast<const bf16x8*>(a1);
    *reinterpret_cast<bf16x8*>(&As[0][r][c0 + 8]) = *reinterpret_cast<const bf16x8*>(a1 + 8);
    *reinterpret_cast<bf16x8*>(&As[1][r][c0])     = *reinterpret_cast<const bf16x8*>(a2);
    *reinterpret_cast<bf16x8*>(&As[1][r][c0 + 8]) = *reinterpret_cast<const bf16x8*>(a2 + 8);
  }
  __syncthreads();
  {
    f32x4 acc1[16], acc2[16];
#pragma unroll
    for (int c = 0; c < 16; ++c) {
      acc1[c] = f32x4{0.f, 0.f, 0.f, 0.f};
      acc2[c] = f32x4{0.f, 0.f, 0.f, 0.f};
    }
#pragma unroll
    for (int kk = 0; kk < 2; ++kk) {
      const bf16x8 a1 = *reinterpret_cast<const bf16x8*>(&As[0][wv * 16 + m][kk * 32 + q * 8]);
      const bf16x8 a2 = *reinterpret_cast<const bf16x8*>(&As[1][wv * 16 + m][kk * 32 + q * 8]);
#pragma unroll
      for (int c = 0; c < 16; ++c) {
        const bf16x8 bf = *reinterpret_cast<const bf16x8*>(&Bs[c * 16 + m][kk * 32 + q * 8]);
        acc1[c] = MFMA16(a1, bf, acc1[c]);
        acc2[c] = MFMA16(a2, bf, acc2[c]);
      }
    }
    float mx1[4] = {0.f, 0.f, 0.f, 0.f}, sm1[4] = {0.f, 0.f, 0.f, 0.f};
    float mx2[4] = {0.f, 0.f, 0.f, 0.f}, sm2[4] = {0.f, 0.f, 0.f, 0.f};
#pragma unroll
    for (int c = 0; c < 16; ++c)
#pragma unroll
      for (int r = 0; r < 4; ++r) {
        mx1[r] = fmaxf(mx1[r], fabsf(acc1[c][r] * SQ));
        mx2[r] = fmaxf(mx2[r], fabsf(acc2[c][r] * SK2));
      }
#pragma unroll
    for (int msk = 1; msk < 16; msk <<= 1)
#pragma unroll
      for (int r = 0; r < 4; ++r) {
        mx1[r] = fmaxf(mx1[r], __shfl_xor(mx1[r], msk));
        mx2[r] = fmaxf(mx2[r], __shfl_xor(mx2[r], msk));
      }
#pragma unroll
    for (int c = 0; c < 16; ++c)
#pragma unroll
      for (int r = 0; r < 4; ++r) {
        const float v1 = acc1[c][r] * SQ, v2 = acc2[c][r] * SK2;
        sm1[r] += __expf(v1 - mx1[r]) + __expf(-v1 - mx1[r]);
        sm2[r] += __expf(v2 - mx2[r]) + __expf(-v2 - mx2[r]);
      }
#pragma unroll
    for (int msk = 1; msk < 16; msk <<= 1)
#pragma unroll
      for (int r = 0; r < 4; ++r) {
        sm1[r] += __shfl_xor(sm1[r], msk);
        sm2[r] += __shfl_xor(sm2[r], msk);
      }

    const long base = ((long)bh * 256 + l0 + wv * 16 + q * 4) * FD;
#pragma unroll
    for (int r = 0; r < 4; ++r) {
      const float w1 = p0w[r] / sm1[r];
      const float w2 = p1w[r] / sm2[r];
      const long rb = base + (long)r * FD;
#pragma unroll
      for (int c = 0; c < 16; ++c) {
        const float v1 = acc1[c][r] * SQ, v2 = acc2[c][r] * SK2;
        const int col = c * 16 + m;
        kf[rb + col] =
            (__bf16)(w1 * __expf(v1 - mx1[r]) + w2 * __expf(v2 - mx2[r]));
        kf[rb + 256 + col] =
            (__bf16)(w1 * __expf(-v1 - mx1[r]) + w2 * __expf(-v2 - mx2[r]));
      }
    }
  }
}

// ---------------------------------------------------------------------------
// K2b: pack V transposed per head: vt[bh][d][s] (validated).
// ---------------------------------------------------------------------------
__global__ __launch_bounds__(256) void vpack(const __bf16* __restrict__ qkv,
                                             __bf16* __restrict__ vt) {
  const int s0 = blockIdx.x * 64;
  const int bh = blockIdx.y;
  const int h = bh & 7, b = bh >> 3;
  __shared__ __bf16 T[64][72];
  const int tid = threadIdx.x;
  {
    const int s = tid >> 2, d0 = (tid & 3) * 16;
    const __bf16* vp = qkv + ((long)((s0 + s) * B_SZ + b)) * QKVN + h * 256 + 192 + d0;
#pragma unroll
    for (int j = 0; j < 16; ++j) T[d0 + j][s] = vp[j];
  }
  __syncthreads();
  {
    const int d = tid >> 2, sc = (tid & 3) * 16;
    __bf16* op = vt + ((long)bh * 64 + d) * 256 + s0 + sc;
    *reinterpret_cast<bf16x8*>(op)     = *reinterpret_cast<const bf16x8*>(&T[d][sc]);
    *reinterpret_cast<bf16x8*>(op + 8) = *reinterpret_cast<const bf16x8*>(&T[d][sc + 8]);
  }
}

// ---------------------------------------------------------------------------
// K3: MFMA flash causal linear attention (validated rounds 3-5).
// ---------------------------------------------------------------------------
__global__ __launch_bounds__(256) void flash_mfma(const __bf16* __restrict__ qf,
                                                  const __bf16* __restrict__ kf,
                                                  const __bf16* __restrict__ vt,
                                                  __bf16* __restrict__ att) {
  const int t0 = blockIdx.x * 64;
  const int bh = blockIdx.y;
  const int h = bh & 7, b = bh >> 3;
  const int tid = threadIdx.x, lane = tid & 63, wv = tid >> 6;
  const int m = lane & 15, q = lane >> 4;
  __shared__ __bf16 Kc[64][136];
  __shared__ __bf16 Vt[80][72];
  __shared__ __bf16 Pt[64][72];

  bf16x8 qreg[16];
  {
    const __bf16* qp = qf + ((long)(bh * 256 + t0 + wv * 16 + m)) * FD + q * 8;
#pragma unroll
    for (int ks = 0; ks < 16; ++ks)
      qreg[ks] = *reinterpret_cast<const bf16x8*>(qp + ks * 32);
  }
  f32x4 oacc[5];
#pragma unroll
  for (int i = 0; i < 5; ++i) oacc[i] = f32x4{0.f, 0.f, 0.f, 0.f};

  const int nst = (t0 >> 6) + 1;
  for (int st = 0; st < nst; ++st) {
    const int s0 = st * 64;
    f32x4 sacc[4];
#pragma unroll
    for (int i = 0; i < 4; ++i) sacc[i] = f32x4{0.f, 0.f, 0.f, 0.f};
    __syncthreads();
    {
      const int d = tid >> 2, sc = (tid & 3) * 16;
      const __bf16* vp = vt + ((long)bh * 64 + d) * 256 + s0 + sc;
      *reinterpret_cast<bf16x8*>(&Vt[d][sc])     = *reinterpret_cast<const bf16x8*>(vp);
      *reinterpret_cast<bf16x8*>(&Vt[d][sc + 8]) = *reinterpret_cast<const bf16x8*>(vp + 8);
      if (tid < 64) Vt[64][tid] = (__bf16)1.0f;
      if (st == 0)
        for (int z = tid; z < 15 * 64; z += 256) Vt[65 + (z >> 6)][z & 63] = (__bf16)0.f;
    }
    for (int ch = 0; ch < 4; ++ch) {
      if (ch) __syncthreads();
      {
        const int r = tid >> 2, c0 = (tid & 3) * 32;
        const __bf16* kp = kf + ((long)(bh * 256 + s0 + r)) * FD + ch * 128 + c0;
#pragma unroll
        for (int j = 0; j < 4; ++j)
          *reinterpret_cast<bf16x8*>(&Kc[r][c0 + j * 8]) =
              *reinterpret_cast<const bf16x8*>(kp + j * 8);
      }
      __syncthreads();
#pragma unroll
      for (int kk = 0; kk < 4; ++kk) {
        const bf16x8 af = qreg[ch * 4 + kk];
#pragma unroll
        for (int c = 0; c < 4; ++c) {
          const bf16x8 bf = *reinterpret_cast<const bf16x8*>(&Kc[c * 16 + m][kk * 32 + q * 8]);
          sacc[c] = MFMA16(af, bf, sacc[c]);
        }
      }
    }
#pragma unroll
    for (int c = 0; c < 4; ++c)
#pragma unroll
      for (int r = 0; r < 4; ++r) {
        const int row = wv * 16 + q * 4 + r, col = c * 16 + m;
        Pt[row][col] = (__bf16)(((s0 + col) <= (t0 + row)) ? sacc[c][r] : 0.f);
      }
#pragma unroll
    for (int kk = 0; kk < 2; ++kk) {
      const bf16x8 pf = *reinterpret_cast<const bf16x8*>(&Pt[wv * 16 + m][kk * 32 + q * 8]);
#pragma unroll
      for (int c = 0; c < 5; ++c) {
        const bf16x8 vf = *reinterpret_cast<const bf16x8*>(&Vt[c * 16 + m][kk * 32 + q * 8]);
        oacc[c] = MFMA16(pf, vf, oacc[c]);
      }
    }
  }
#pragma unroll
  for (int r = 0; r < 4; ++r) {
    const float den = __shfl(oacc[4][r], (lane & 48));
    const float inv = 0.125f / (den + 1e-5f);           // SCALE=64^-0.5, EPS
    const int row = t0 + wv * 16 + q * 4 + r;
#pragma unroll
    for (int c = 0; c < 4; ++c)
      att[((long)(row * B_SZ + b)) * DM + h * DH + c * 16 + m] = (__bf16)(oacc[c][r] * inv);
  }
}

// ---------------------------------------------------------------------------
// K4: xrow = hb + att @ w_o (f32 out), MFMA (validated rounds 4-5).
// ---------------------------------------------------------------------------
__global__ __launch_bounds__(256) void gemm_att_wo(const __bf16* __restrict__ A,
                                                   const __bf16* __restrict__ Bt,
                                                   const __bf16* __restrict__ hb,
                                                   float* __restrict__ xrow) {
  __shared__ __bf16 At[64][136];
  __shared__ __bf16 Bts[64][136];
  const int n0 = blockIdx.x * 64, m0 = blockIdx.y * 64;
  const int tid = threadIdx.x, lane = tid & 63, wv = tid >> 6;
  const int m = lane & 15, q = lane >> 4;
  f32x4 acc[4];
#pragma unroll
  for (int i = 0; i < 4; ++i) acc[i] = f32x4{0.f, 0.f, 0.f, 0.f};

  for (int k0 = 0; k0 < DM; k0 += 128) {
    __syncthreads();
    {
      const int r = tid >> 2, c0 = (tid & 3) * 32;
      const __bf16* ap = A + (long)(m0 + r) * DM + k0 + c0;
      const __bf16* bp = Bt + (long)(n0 + r) * DM + k0 + c0;
#pragma unroll
      for (int j4 = 0; j4 < 4; ++j4) {
        *reinterpret_cast<bf16x8*>(&At[r][c0 + j4 * 8]) =
            *reinterpret_cast<const bf16x8*>(ap + j4 * 8);
        *reinterpret_cast<bf16x8*>(&Bts[r][c0 + j4 * 8]) =
            *reinterpret_cast<const bf16x8*>(bp + j4 * 8);
      }
    }
    __syncthreads();
#pragma unroll
    for (int kk = 0; kk < 4; ++kk) {
      const bf16x8 af = *reinterpret_cast<const bf16x8*>(&At[wv * 16 + m][kk * 32 + q * 8]);
#pragma unroll
      for (int c = 0; c < 4; ++c) {
        const bf16x8 bf = *reinterpret_cast<const bf16x8*>(&Bts[c * 16 + m][kk * 32 + q * 8]);
        acc[c] = MFMA16(af, bf, acc[c]);
      }
    }
  }
#pragma unroll
  for (int r = 0; r < 4; ++r)
#pragma unroll
    for (int c = 0; c < 4; ++c) {
      const long row = m0 + wv * 16 + q * 4 + r;
      const long col = n0 + c * 16 + m;
      xrow[row * DM + col] = acc[c][r] + (float)hb[row * DM + col];
    }
}

// ---------------------------------------------------------------------------
// K5: LayerNorm rows of xrow -> out (validated rounds 4-5).
// ---------------------------------------------------------------------------
__global__ __launch_bounds__(256) void ln_out(const float* __restrict__ xrow,
                                              const __bf16* __restrict__ gamma,
                                              const __bf16* __restrict__ beta,
                                              const int* __restrict__ flag,
                                              void* __restrict__ out) {
  const int f32 = flag[0];
  const int r = blockIdx.x;
  const int tid = threadIdx.x;
  __shared__ float red[256];
  const float x0 = xrow[(long)r * DM + tid];
  const float x1 = xrow[(long)r * DM + tid + 256];

  red[tid] = x0 + x1; __syncthreads();
  for (int s = 128; s > 0; s >>= 1) { if (tid < s) red[tid] += red[tid + s]; __syncthreads(); }
  const float mu = red[0] * (1.f / 512.f); __syncthreads();
  red[tid] = x0 * x0 + x1 * x1; __syncthreads();
  for (int s = 128; s > 0; s >>= 1) { if (tid < s) red[tid] += red[tid + s]; __syncthreads(); }
  const float var = red[0] * (1.f / 512.f) - mu * mu; __syncthreads();
  const float rstd = rsqrtf(var + 1e-5f);

  stmix(out, (long)r * DM + tid,
        (x0 - mu) * rstd * (float)gamma[tid] + (float)beta[tid], f32);
  stmix(out, (long)r * DM + tid + 256,
        (x1 - mu) * rstd * (float)gamma[tid + 256] + (float)beta[tid + 256], f32);
}

// ---------------------------------------------------------------------------
extern "C" void kernel_launch(void* const* d_in, const int* in_sizes, int n_in,
                              void* d_out, int out_size, void* d_ws, size_t ws_size,
                              hipStream_t stream) {
  (void)in_sizes; (void)n_in; (void)out_size; (void)ws_size;
  // Workspace layout (bytes):
  //   qkv   bf16 [8192,2048]   @ 0           33,554,432
  //   flag  int                @ 33,554,432  256
  //   wt    bf16 [2048,512]    @ 33,554,688  2,097,152   (w_qkv^T)
  //   wot   bf16 [512,512]     @ 35,651,840  524,288     (w_o^T)
  //   att   bf16 [8192,512]    @ 36,176,128  8,388,608
  //   vt    bf16 [256,64,256]  @ 44,564,736  8,388,608
  //   hb    bf16 [8192,512]    @ 52,953,344  8,388,608
  //   projT bf16 [256,64]      @ 61,341,952  32,768      (proj^T)
  //   pi0b  bf16 [8,256]       @ 61,374,720  4,096
  //   pi1b  bf16 [8,256]       @ 61,378,816  4,096
  //   gamb  bf16 [512]         @ 61,382,912  1,024
  //   betb  bf16 [512]         @ 61,383,936  1,024
  //   qf    bf16 [256,256,512] @ 61,384,960  67,108,864
  //   kf    bf16 [256,256,512] @ 128,493,824 67,108,864
  //   xrow  f32  [8192,512]    @ 61,384,960  (aliases qf; used after flash)
  char* ws = (char*)d_ws;
  __bf16* qkv   = (__bf16*)ws;
  int*    flag  = (int*)(ws + 33554432);
  __bf16* wt    = (__bf16*)(ws + 33554688);
  __bf16* wot   = (__bf16*)(ws + 35651840);
  __bf16* att   = (__bf16*)(ws + 36176128);
  __bf16* vt    = (__bf16*)(ws + 44564736);
  __bf16* hb    = (__bf16*)(ws + 52953344);
  __bf16* projT = (__bf16*)(ws + 61341952);
  __bf16* pi0b  = (__bf16*)(ws + 61374720);
  __bf16* pi1b  = (__bf16*)(ws + 61378816);
  __bf16* gamb  = (__bf16*)(ws + 61382912);
  __bf16* betb  = (__bf16*)(ws + 61383936);
  __bf16* qf    = (__bf16*)(ws + 61384960);
  __bf16* kf    = (__bf16*)(ws + 128493824);
  float*  xrow  = (float*)(ws + 61384960);   // aliases qf

  small_prep<<<5, 256, 0, stream>>>((const unsigned short*)d_in[0], d_in[5], d_in[6],
                                    d_in[3], d_in[4], flag, pi0b, pi1b, gamb, betb);
  cvt_bf16<<<2048, 256, 0, stream>>>(d_in[0], hb, flag, ROWS * DM / 8);        // h
  transpose_bf<<<dim3(32, 8), 256, 0, stream>>>(d_in[1], flag, wt, 512, 2048); // w_qkv^T
  transpose_bf<<<dim3(8, 8), 256, 0, stream>>>(d_in[2], flag, wot, 512, 512);  // w_o^T
  transpose_bf<<<dim3(4, 1), 256, 0, stream>>>(d_in[7], flag, projT, 64, 256); // proj^T

  gemm_h_wqkv<<<dim3(32, 128), 256, 0, stream>>>(hb, wt, qkv);
  vpack<<<dim3(4, 256), 256, 0, stream>>>(qkv, vt);
  features_mfma<<<dim3(4, 256), 256, 0, stream>>>(qkv, projT, pi0b, pi1b, qf, kf);
  flash_mfma<<<dim3(4, 256), 256, 0, stream>>>(qf, kf, vt, att);
  gemm_att_wo<<<dim3(8, 128), 256, 0, stream>>>(att, wot, hb, xrow);
  ln_out<<<dim3(ROWS), 256, 0, stream>>>(xrow, gamb, betb, flag, d_out);
}

// Round 7
// 277.462 us; speedup vs baseline: 7.0780x; 1.0799x over previous
//
#include <hip/hip_runtime.h>
#include <hip/hip_bf16.h>

// L=256, B=32, H=8, d_head=64, m=256, feature dim 2m=512, D_MODEL=512
#define L_SEQ 256
#define B_SZ  32
#define NH    8
#define DH    64
#define DM    512
#define FD    512
#define PM    256
#define ROWS  8192
#define QKVN  2048

typedef __bf16 bf16x8 __attribute__((ext_vector_type(8)));
typedef float f32x4 __attribute__((ext_vector_type(4)));
#define MFMA16(a, b, c) __builtin_amdgcn_mfma_f32_16x16x32_bf16((a), (b), (c), 0, 0, 0)

static __device__ __forceinline__ void stmix(void* p, long i, float v, int f32) {
  if (f32) ((float*)p)[i] = v;
  else     ((__bf16*)p)[i] = (__bf16)v;
}

// ---------------------------------------------------------------------------
// P0: prep — one kernel replacing probe+cvt(h)+3 transposes+tiny cvts.
// Every block re-derives the dtype flag inline from h's first 8 KB (bf16
// N(0,1): no exponent >= 0xA0; f32-as-u16 odd halves: ~37% there) — no
// cross-block dependency. Block roles by blockIdx.x range.
// ---------------------------------------------------------------------------
#define PREP_HB   2048          // [0,2048):      h -> hb cvt (8 elems/thread)
#define PREP_WT   256           // [2048,2304):   w_qkv^T tiles
#define PREP_WOT  64            // [2304,2368):   w_o^T tiles
#define PREP_PJ   4             // [2368,2372):   proj^T tiles
#define PREP_TINY 1             // 2372:          pi0/pi1/gamma/beta + flag
#define PREP_BLOCKS (PREP_HB + PREP_WT + PREP_WOT + PREP_PJ + PREP_TINY)

__global__ __launch_bounds__(256) void prep(
    const void* __restrict__ h, const void* __restrict__ wqkv,
    const void* __restrict__ wo, const void* __restrict__ proj,
    const void* __restrict__ pi0, const void* __restrict__ pi1,
    const void* __restrict__ gam, const void* __restrict__ bet,
    int* __restrict__ flag, __bf16* __restrict__ hb, __bf16* __restrict__ wt,
    __bf16* __restrict__ wot, __bf16* __restrict__ projT,
    __bf16* __restrict__ pi0b, __bf16* __restrict__ pi1b,
    __bf16* __restrict__ gamb, __bf16* __restrict__ betb) {
  __shared__ float T[64][69];
  __shared__ int red[256];
  const int tid = threadIdx.x;
  // inline dtype probe (proven method, rounds 2-6)
  int cnt = 0;
  {
    const unsigned short* hbits = (const unsigned short*)h;
    for (int i = 0; i < 16; ++i) {
      const unsigned short u = hbits[tid * 16 + i];
      if (((u >> 7) & 0xFF) >= 0xA0) ++cnt;
    }
  }
  red[tid] = cnt; __syncthreads();
  for (int s = 128; s > 0; s >>= 1) { if (tid < s) red[tid] += red[tid + s]; __syncthreads(); }
  const int f32 = (red[0] >= 64) ? 1 : 0;
  __syncthreads();

  const int blk = blockIdx.x;
  if (blk < PREP_HB) {
    // h -> hb, vectorized
    const int i = blk * 256 + tid;            // < ROWS*DM/8 = 524288 exactly
    if (f32) {
      const f32x4* s = (const f32x4*)h;
      const f32x4 a = s[i * 2], b = s[i * 2 + 1];
      bf16x8 t;
      t[0] = (__bf16)a[0]; t[1] = (__bf16)a[1]; t[2] = (__bf16)a[2]; t[3] = (__bf16)a[3];
      t[4] = (__bf16)b[0]; t[5] = (__bf16)b[1]; t[6] = (__bf16)b[2]; t[7] = (__bf16)b[3];
      *reinterpret_cast<bf16x8*>(hb + (long)i * 8) = t;
    } else {
      *reinterpret_cast<bf16x8*>(hb + (long)i * 8) = ((const bf16x8*)h)[i];
    }
    return;
  }
  // transpose roles
  const void* src; __bf16* dst; int M, N, n0, m0;
  if (blk < PREP_HB + PREP_WT) {
    const int x = blk - PREP_HB;
    src = wqkv; dst = wt; M = 512; N = 2048; n0 = (x & 31) * 64; m0 = (x >> 5) * 64;
  } else if (blk < PREP_HB + PREP_WT + PREP_WOT) {
    const int x = blk - PREP_HB - PREP_WT;
    src = wo; dst = wot; M = 512; N = 512; n0 = (x & 7) * 64; m0 = (x >> 3) * 64;
  } else if (blk < PREP_HB + PREP_WT + PREP_WOT + PREP_PJ) {
    const int x = blk - PREP_HB - PREP_WT - PREP_WOT;
    src = proj; dst = projT; M = 64; N = 256; n0 = x * 64; m0 = 0;
  } else {
    // tiny conversions + flag publish
    if (tid == 0) flag[0] = f32;
    if (f32) {
      const float* s0 = (const float*)pi0; const float* s1 = (const float*)pi1;
      const float* s2 = (const float*)gam; const float* s3 = (const float*)bet;
      for (int i = tid; i < NH * 256; i += 256) { pi0b[i] = (__bf16)s0[i]; pi1b[i] = (__bf16)s1[i]; }
      for (int i = tid; i < DM; i += 256)      { gamb[i] = (__bf16)s2[i]; betb[i] = (__bf16)s3[i]; }
    } else {
      const __bf16* s0 = (const __bf16*)pi0; const __bf16* s1 = (const __bf16*)pi1;
      const __bf16* s2 = (const __bf16*)gam; const __bf16* s3 = (const __bf16*)bet;
      for (int i = tid; i < NH * 256; i += 256) { pi0b[i] = s0[i]; pi1b[i] = s1[i]; }
      for (int i = tid; i < DM; i += 256)      { gamb[i] = s2[i]; betb[i] = s3[i]; }
    }
    return;
  }
  // 64x64 transpose tile (validated rounds 4-6)
  if (f32) {
    const float* s = (const float*)src;
#pragma unroll
    for (int rep = 0; rep < 16; ++rep) {
      const int i = rep * 4 + (tid >> 6), j = tid & 63;
      T[i][j] = s[(long)(m0 + i) * N + n0 + j];
    }
  } else {
    const __bf16* s = (const __bf16*)src;
#pragma unroll
    for (int rep = 0; rep < 16; ++rep) {
      const int i = rep * 4 + (tid >> 6), j = tid & 63;
      T[i][j] = (float)s[(long)(m0 + i) * N + n0 + j];
    }
  }
  __syncthreads();
#pragma unroll
  for (int rep = 0; rep < 16; ++rep) {
    const int i = rep * 4 + (tid >> 6), j = tid & 63;
    dst[(long)(n0 + i) * M + m0 + j] = (__bf16)T[j][i];
  }
}

// ---------------------------------------------------------------------------
// K1: qkv = hb @ w_qkv via MFMA, with register prefetch of the next K-chunk
// (global load latency overlapped with current chunk's MFMA).
// ---------------------------------------------------------------------------
__global__ __launch_bounds__(256) void gemm_h_wqkv(const __bf16* __restrict__ A,
                                                   const __bf16* __restrict__ Bt,
                                                   __bf16* __restrict__ C) {
  __shared__ __bf16 At[64][136];
  __shared__ __bf16 Bts[64][136];
  const int n0 = blockIdx.x * 64, m0 = blockIdx.y * 64;
  const int tid = threadIdx.x, lane = tid & 63, wv = tid >> 6;
  const int m = lane & 15, q = lane >> 4;
  const int r = tid >> 2, c0 = (tid & 3) * 32;
  const __bf16* ap = A + (long)(m0 + r) * DM + c0;
  const __bf16* bp = Bt + (long)(n0 + r) * DM + c0;
  f32x4 acc[4];
#pragma unroll
  for (int i = 0; i < 4; ++i) acc[i] = f32x4{0.f, 0.f, 0.f, 0.f};

  bf16x8 ar[4], br[4];
#pragma unroll
  for (int j = 0; j < 4; ++j) {
    ar[j] = *reinterpret_cast<const bf16x8*>(ap + j * 8);
    br[j] = *reinterpret_cast<const bf16x8*>(bp + j * 8);
  }
  for (int k0 = 0; k0 < DM; k0 += 128) {
    __syncthreads();
#pragma unroll
    for (int j = 0; j < 4; ++j) {
      *reinterpret_cast<bf16x8*>(&At[r][c0 + j * 8]) = ar[j];
      *reinterpret_cast<bf16x8*>(&Bts[r][c0 + j * 8]) = br[j];
    }
    if (k0 + 128 < DM) {
#pragma unroll
      for (int j = 0; j < 4; ++j) {
        ar[j] = *reinterpret_cast<const bf16x8*>(ap + k0 + 128 + j * 8);
        br[j] = *reinterpret_cast<const bf16x8*>(bp + k0 + 128 + j * 8);
      }
    }
    __syncthreads();
#pragma unroll
    for (int kk = 0; kk < 4; ++kk) {
      const bf16x8 af = *reinterpret_cast<const bf16x8*>(&At[wv * 16 + m][kk * 32 + q * 8]);
#pragma unroll
      for (int c = 0; c < 4; ++c) {
        const bf16x8 bf = *reinterpret_cast<const bf16x8*>(&Bts[c * 16 + m][kk * 32 + q * 8]);
        acc[c] = MFMA16(af, bf, acc[c]);
      }
    }
  }
#pragma unroll
  for (int r2 = 0; r2 < 4; ++r2)
#pragma unroll
    for (int c = 0; c < 4; ++c)
      C[(long)(m0 + wv * 16 + q * 4 + r2) * QKVN + n0 + c * 16 + m] = (__bf16)acc[c][r2];
}

// ---------------------------------------------------------------------------
// K2: Performer features, MFMA + in-register softmax (validated round 5/6).
// Round-7: all three A-tiles (q,k1,k2) + projT staged up front -> ONE barrier,
// no mid-kernel global-load stalls. norm(prime(x,P)) == softmax([xP,-xP]).
// ---------------------------------------------------------------------------
__global__ __launch_bounds__(256) void features_mfma(const __bf16* __restrict__ qkv,
                                                     const __bf16* __restrict__ projT,
                                                     const __bf16* __restrict__ pi0,
                                                     const __bf16* __restrict__ pi1,
                                                     __bf16* __restrict__ qf,
                                                     __bf16* __restrict__ kf) {
  const int l0 = blockIdx.x * 64;
  const int bh = blockIdx.y;
  const int h = bh & 7, b = bh >> 3;
  const int tid = threadIdx.x, lane = tid & 63, wv = tid >> 6;
  const int m = lane & 15, q = lane >> 4;
  __shared__ __bf16 Bs[256][72];     // projT rows (n=proj col, k=d)
  __shared__ __bf16 As[3][64][72];   // q / k1 / k2 tiles: 64 l-rows x 64 d

  {
    const __bf16* p = projT + (long)tid * 64;
#pragma unroll
    for (int j = 0; j < 8; ++j)
      *reinterpret_cast<bf16x8*>(&Bs[tid][j * 8]) = *reinterpret_cast<const bf16x8*>(p + j * 8);
  }
  {
    const int r = tid >> 2, c0 = (tid & 3) * 16;
    const __bf16* ap = qkv + (long)((l0 + r) * B_SZ + b) * QKVN + h * 256 + c0;
#pragma unroll
    for (int t3 = 0; t3 < 3; ++t3) {
      *reinterpret_cast<bf16x8*>(&As[t3][r][c0]) =
          *reinterpret_cast<const bf16x8*>(ap + t3 * 64);
      *reinterpret_cast<bf16x8*>(&As[t3][r][c0 + 8]) =
          *reinterpret_cast<const bf16x8*>(ap + t3 * 64 + 8);
    }
  }
  float p0w[4], p1w[4];
#pragma unroll
  for (int r = 0; r < 4; ++r) {
    const int l = l0 + wv * 16 + q * 4 + r;
    p0w[r] = (float)pi0[h * 256 + l];
    p1w[r] = (float)pi1[h * 256 + l];
  }
  const float SQ = 0.35355339f;      // 64^-0.25
  const float SK2 = 0.24748737f;     // 0.7 * 64^-0.25
  __syncthreads();                   // the only barrier

  // ---- phase Q ----
  {
    f32x4 acc[16];
#pragma unroll
    for (int c = 0; c < 16; ++c) acc[c] = f32x4{0.f, 0.f, 0.f, 0.f};
#pragma unroll
    for (int kk = 0; kk < 2; ++kk) {
      const bf16x8 af = *reinterpret_cast<const bf16x8*>(&As[0][wv * 16 + m][kk * 32 + q * 8]);
#pragma unroll
      for (int c = 0; c < 16; ++c) {
        const bf16x8 bf = *reinterpret_cast<const bf16x8*>(&Bs[c * 16 + m][kk * 32 + q * 8]);
        acc[c] = MFMA16(af, bf, acc[c]);
      }
    }
    float mx[4] = {0.f, 0.f, 0.f, 0.f}, sm[4] = {0.f, 0.f, 0.f, 0.f};
#pragma unroll
    for (int c = 0; c < 16; ++c)
#pragma unroll
      for (int r = 0; r < 4; ++r) mx[r] = fmaxf(mx[r], fabsf(acc[c][r] * SQ));
#pragma unroll
    for (int msk = 1; msk < 16; msk <<= 1)
#pragma unroll
      for (int r = 0; r < 4; ++r) mx[r] = fmaxf(mx[r], __shfl_xor(mx[r], msk));
#pragma unroll
    for (int c = 0; c < 16; ++c)
#pragma unroll
      for (int r = 0; r < 4; ++r) {
        const float v = acc[c][r] * SQ;
        sm[r] += __expf(v - mx[r]) + __expf(-v - mx[r]);
      }
#pragma unroll
    for (int msk = 1; msk < 16; msk <<= 1)
#pragma unroll
      for (int r = 0; r < 4; ++r) sm[r] += __shfl_xor(sm[r], msk);

    const long base = ((long)bh * 256 + l0 + wv * 16 + q * 4) * FD;
#pragma unroll
    for (int r = 0; r < 4; ++r) {
      const float inv = 1.f / sm[r];
      const long rb = base + (long)r * FD;
#pragma unroll
      for (int c = 0; c < 16; ++c) {
        const float v = acc[c][r] * SQ;
        const int col = c * 16 + m;
        qf[rb + col]       = (__bf16)(__expf(v - mx[r]) * inv);
        qf[rb + 256 + col] = (__bf16)(__expf(-v - mx[r]) * inv);
      }
    }
  }

  // ---- phase K1+K2 (fused, single kf write pass) ----
  {
    f32x4 acc1[16], acc2[16];
#pragma unroll
    for (int c = 0; c < 16; ++c) {
      acc1[c] = f32x4{0.f, 0.f, 0.f, 0.f};
      acc2[c] = f32x4{0.f, 0.f, 0.f, 0.f};
    }
#pragma unroll
    for (int kk = 0; kk < 2; ++kk) {
      const bf16x8 a1 = *reinterpret_cast<const bf16x8*>(&As[1][wv * 16 + m][kk * 32 + q * 8]);
      const bf16x8 a2 = *reinterpret_cast<const bf16x8*>(&As[2][wv * 16 + m][kk * 32 + q * 8]);
#pragma unroll
      for (int c = 0; c < 16; ++c) {
        const bf16x8 bf = *reinterpret_cast<const bf16x8*>(&Bs[c * 16 + m][kk * 32 + q * 8]);
        acc1[c] = MFMA16(a1, bf, acc1[c]);
        acc2[c] = MFMA16(a2, bf, acc2[c]);
      }
    }
    float mx1[4] = {0.f, 0.f, 0.f, 0.f}, sm1[4] = {0.f, 0.f, 0.f, 0.f};
    float mx2[4] = {0.f, 0.f, 0.f, 0.f}, sm2[4] = {0.f, 0.f, 0.f, 0.f};
#pragma unroll
    for (int c = 0; c < 16; ++c)
#pragma unroll
      for (int r = 0; r < 4; ++r) {
        mx1[r] = fmaxf(mx1[r], fabsf(acc1[c][r] * SQ));
        mx2[r] = fmaxf(mx2[r], fabsf(acc2[c][r] * SK2));
      }
#pragma unroll
    for (int msk = 1; msk < 16; msk <<= 1)
#pragma unroll
      for (int r = 0; r < 4; ++r) {
        mx1[r] = fmaxf(mx1[r], __shfl_xor(mx1[r], msk));
        mx2[r] = fmaxf(mx2[r], __shfl_xor(mx2[r], msk));
      }
#pragma unroll
    for (int c = 0; c < 16; ++c)
#pragma unroll
      for (int r = 0; r < 4; ++r) {
        const float v1 = acc1[c][r] * SQ, v2 = acc2[c][r] * SK2;
        sm1[r] += __expf(v1 - mx1[r]) + __expf(-v1 - mx1[r]);
        sm2[r] += __expf(v2 - mx2[r]) + __expf(-v2 - mx2[r]);
      }
#pragma unroll
    for (int msk = 1; msk < 16; msk <<= 1)
#pragma unroll
      for (int r = 0; r < 4; ++r) {
        sm1[r] += __shfl_xor(sm1[r], msk);
        sm2[r] += __shfl_xor(sm2[r], msk);
      }
    const long base = ((long)bh * 256 + l0 + wv * 16 + q * 4) * FD;
#pragma unroll
    for (int r = 0; r < 4; ++r) {
      const float w1 = p0w[r] / sm1[r];
      const float w2 = p1w[r] / sm2[r];
      const long rb = base + (long)r * FD;
#pragma unroll
      for (int c = 0; c < 16; ++c) {
        const float v1 = acc1[c][r] * SQ, v2 = acc2[c][r] * SK2;
        const int col = c * 16 + m;
        kf[rb + col] =
            (__bf16)(w1 * __expf(v1 - mx1[r]) + w2 * __expf(v2 - mx2[r]));
        kf[rb + 256 + col] =
            (__bf16)(w1 * __expf(-v1 - mx1[r]) + w2 * __expf(-v2 - mx2[r]));
      }
    }
  }
}

// ---------------------------------------------------------------------------
// K2b: pack V transposed per head: vt[bh][d][s] (validated).
// ---------------------------------------------------------------------------
__global__ __launch_bounds__(256) void vpack(const __bf16* __restrict__ qkv,
                                             __bf16* __restrict__ vt) {
  const int s0 = blockIdx.x * 64;
  const int bh = blockIdx.y;
  const int h = bh & 7, b = bh >> 3;
  __shared__ __bf16 T[64][72];
  const int tid = threadIdx.x;
  {
    const int s = tid >> 2, d0 = (tid & 3) * 16;
    const __bf16* vp = qkv + ((long)((s0 + s) * B_SZ + b)) * QKVN + h * 256 + 192 + d0;
#pragma unroll
    for (int j = 0; j < 16; ++j) T[d0 + j][s] = vp[j];
  }
  __syncthreads();
  {
    const int d = tid >> 2, sc = (tid & 3) * 16;
    __bf16* op = vt + ((long)bh * 64 + d) * 256 + s0 + sc;
    *reinterpret_cast<bf16x8*>(op)     = *reinterpret_cast<const bf16x8*>(&T[d][sc]);
    *reinterpret_cast<bf16x8*>(op + 8) = *reinterpret_cast<const bf16x8*>(&T[d][sc + 8]);
  }
}

// ---------------------------------------------------------------------------
// K3: MFMA flash causal linear attention — round-7 restructure.
// Block = (pair, bh): pair 0 owns t-tiles {0,3}, pair 1 owns {1,2} — every
// block does exactly 5 QK-tile combos + 5 PV (perfect balance; kf stagings
// per bh 10 -> 7). Both t-tiles share the staged B-fragments (2x MFMA per
// barrier). K-chunk and V-tile global loads are register-prefetched during
// the previous chunk's MFMA phase, so barriers no longer enclose HBM latency.
// ---------------------------------------------------------------------------
__global__ __launch_bounds__(256, 2) void flash_mfma(const __bf16* __restrict__ qf,
                                                     const __bf16* __restrict__ kf,
                                                     const __bf16* __restrict__ vt,
                                                     __bf16* __restrict__ att) {
  const int pr = blockIdx.x;              // 0:{0,3}  1:{1,2}
  const int bh = blockIdx.y;
  const int h = bh & 7, b = bh >> 3;
  const int tid = threadIdx.x, lane = tid & 63, wv = tid >> 6;
  const int m = lane & 15, q = lane >> 4;
  const int tA = pr, tB = 3 - pr;
  __shared__ __bf16 Kc[64][136];
  __shared__ __bf16 Vt[80][72];
  __shared__ __bf16 Pt[64][72];

  // Q fragments for both tiles (held in registers, K=512)
  bf16x8 qA[16], qB[16];
  {
    const __bf16* qpA = qf + ((long)(bh * 256 + tA * 64 + wv * 16 + m)) * FD + q * 8;
    const __bf16* qpB = qf + ((long)(bh * 256 + tB * 64 + wv * 16 + m)) * FD + q * 8;
#pragma unroll
    for (int ks = 0; ks < 16; ++ks) {
      qA[ks] = *reinterpret_cast<const bf16x8*>(qpA + ks * 32);
      qB[ks] = *reinterpret_cast<const bf16x8*>(qpB + ks * 32);
    }
  }
  f32x4 oA[5], oB[5];
#pragma unroll
  for (int i = 0; i < 5; ++i) { oA[i] = f32x4{0.f, 0.f, 0.f, 0.f}; oB[i] = oA[i]; }

  // static Vt rows: ones (denominator column source) + zero padding
  if (tid < 64) Vt[64][tid] = (__bf16)1.0f;
  for (int z = tid; z < 15 * 64; z += 256) Vt[65 + (z >> 6)][z & 63] = (__bf16)0.f;

  // prefetch st=0: V rows + K chunk0
  const int vrow = tid >> 2, vc0 = (tid & 3) * 16;
  const int krow = tid >> 2, kc0 = (tid & 3) * 32;
  const __bf16* vbase = vt + ((long)bh * 64 + vrow) * 256 + vc0;
  const __bf16* kbase = kf + ((long)(bh * 256 + krow)) * FD + kc0;
  bf16x8 vr0, vr1, kr[4];
  vr0 = *reinterpret_cast<const bf16x8*>(vbase);
  vr1 = *reinterpret_cast<const bf16x8*>(vbase + 8);
#pragma unroll
  for (int j = 0; j < 4; ++j) kr[j] = *reinterpret_cast<const bf16x8*>(kbase + j * 8);

  for (int st = 0; st <= tB; ++st) {
    const bool aA = (st <= tA);
    f32x4 sA[4], sB[4];
#pragma unroll
    for (int i = 0; i < 4; ++i) { sA[i] = f32x4{0.f, 0.f, 0.f, 0.f}; sB[i] = sA[i]; }
#pragma unroll
    for (int ch = 0; ch < 4; ++ch) {
      __syncthreads();                       // prev chunk's reads complete
      if (ch == 0) {
        *reinterpret_cast<bf16x8*>(&Vt[vrow][vc0])     = vr0;
        *reinterpret_cast<bf16x8*>(&Vt[vrow][vc0 + 8]) = vr1;
      }
#pragma unroll
      for (int j = 0; j < 4; ++j)
        *reinterpret_cast<bf16x8*>(&Kc[krow][kc0 + j * 8]) = kr[j];
      // register-prefetch the next chunk / next s-tile
      if (ch < 3) {
        const __bf16* kp = kbase + (long)st * 64 * FD + (ch + 1) * 128;
#pragma unroll
        for (int j = 0; j < 4; ++j) kr[j] = *reinterpret_cast<const bf16x8*>(kp + j * 8);
      } else if (st < tB) {
        const __bf16* kp = kbase + (long)(st + 1) * 64 * FD;
#pragma unroll
        for (int j = 0; j < 4; ++j) kr[j] = *reinterpret_cast<const bf16x8*>(kp + j * 8);
        vr0 = *reinterpret_cast<const bf16x8*>(vbase + (st + 1) * 64);
        vr1 = *reinterpret_cast<const bf16x8*>(vbase + (st + 1) * 64 + 8);
      }
      __syncthreads();                       // staged data visible
#pragma unroll
      for (int kk = 0; kk < 4; ++kk) {
#pragma unroll
        for (int c = 0; c < 4; ++c) {
          const bf16x8 bf = *reinterpret_cast<const bf16x8*>(&Kc[c * 16 + m][kk * 32 + q * 8]);
          sB[c] = MFMA16(qB[ch * 4 + kk], bf, sB[c]);
          if (aA) sA[c] = MFMA16(qA[ch * 4 + kk], bf, sA[c]);
        }
      }
    }
    // P -> LDS (C->A layout; rows wave-private: no barrier) + PV, tile B
    {
      const bool mask = (st == tB);
#pragma unroll
      for (int c = 0; c < 4; ++c)
#pragma unroll
        for (int r = 0; r < 4; ++r) {
          const int row = wv * 16 + q * 4 + r, col = c * 16 + m;
          Pt[row][col] = (__bf16)((mask && col > row) ? 0.f : sB[c][r]);
        }
#pragma unroll
      for (int kk = 0; kk < 2; ++kk) {
        const bf16x8 pf = *reinterpret_cast<const bf16x8*>(&Pt[wv * 16 + m][kk * 32 + q * 8]);
#pragma unroll
        for (int c = 0; c < 5; ++c) {
          const bf16x8 vf = *reinterpret_cast<const bf16x8*>(&Vt[c * 16 + m][kk * 32 + q * 8]);
          oB[c] = MFMA16(pf, vf, oB[c]);
        }
      }
    }
    if (aA) {
      const bool mask = (st == tA);
#pragma unroll
      for (int c = 0; c < 4; ++c)
#pragma unroll
        for (int r = 0; r < 4; ++r) {
          const int row = wv * 16 + q * 4 + r, col = c * 16 + m;
          Pt[row][col] = (__bf16)((mask && col > row) ? 0.f : sA[c][r]);
        }
#pragma unroll
      for (int kk = 0; kk < 2; ++kk) {
        const bf16x8 pf = *reinterpret_cast<const bf16x8*>(&Pt[wv * 16 + m][kk * 32 + q * 8]);
#pragma unroll
        for (int c = 0; c < 5; ++c) {
          const bf16x8 vf = *reinterpret_cast<const bf16x8*>(&Vt[c * 16 + m][kk * 32 + q * 8]);
          oA[c] = MFMA16(pf, vf, oA[c]);
        }
      }
    }
  }
  // epilogue: both tiles
#pragma unroll
  for (int r = 0; r < 4; ++r) {
    const float denB = __shfl(oB[4][r], (lane & 48));
    const float invB = 0.125f / (denB + 1e-5f);          // SCALE=64^-0.5, EPS
    const int rowB = tB * 64 + wv * 16 + q * 4 + r;
#pragma unroll
    for (int c = 0; c < 4; ++c)
      att[((long)(rowB * B_SZ + b)) * DM + h * DH + c * 16 + m] = (__bf16)(oB[c][r] * invB);
    const float denA = __shfl(oA[4][r], (lane & 48));
    const float invA = 0.125f / (denA + 1e-5f);
    const int rowA = tA * 64 + wv * 16 + q * 4 + r;
#pragma unroll
    for (int c = 0; c < 4; ++c)
      att[((long)(rowA * B_SZ + b)) * DM + h * DH + c * 16 + m] = (__bf16)(oA[c][r] * invA);
  }
}

// ---------------------------------------------------------------------------
// K4: xrow = hb + att @ w_o (f32 out), MFMA with register prefetch.
// ---------------------------------------------------------------------------
__global__ __launch_bounds__(256) void gemm_att_wo(const __bf16* __restrict__ A,
                                                   const __bf16* __restrict__ Bt,
                                                   const __bf16* __restrict__ hb,
                                                   float* __restrict__ xrow) {
  __shared__ __bf16 At[64][136];
  __shared__ __bf16 Bts[64][136];
  const int n0 = blockIdx.x * 64, m0 = blockIdx.y * 64;
  const int tid = threadIdx.x, lane = tid & 63, wv = tid >> 6;
  const int m = lane & 15, q = lane >> 4;
  const int r = tid >> 2, c0 = (tid & 3) * 32;
  const __bf16* ap = A + (long)(m0 + r) * DM + c0;
  const __bf16* bp = Bt + (long)(n0 + r) * DM + c0;
  f32x4 acc[4];
#pragma unroll
  for (int i = 0; i < 4; ++i) acc[i] = f32x4{0.f, 0.f, 0.f, 0.f};

  bf16x8 ar[4], br[4];
#pragma unroll
  for (int j = 0; j < 4; ++j) {
    ar[j] = *reinterpret_cast<const bf16x8*>(ap + j * 8);
    br[j] = *reinterpret_cast<const bf16x8*>(bp + j * 8);
  }
  for (int k0 = 0; k0 < DM; k0 += 128) {
    __syncthreads();
#pragma unroll
    for (int j = 0; j < 4; ++j) {
      *reinterpret_cast<bf16x8*>(&At[r][c0 + j * 8]) = ar[j];
      *reinterpret_cast<bf16x8*>(&Bts[r][c0 + j * 8]) = br[j];
    }
    if (k0 + 128 < DM) {
#pragma unroll
      for (int j = 0; j < 4; ++j) {
        ar[j] = *reinterpret_cast<const bf16x8*>(ap + k0 + 128 + j * 8);
        br[j] = *reinterpret_cast<const bf16x8*>(bp + k0 + 128 + j * 8);
      }
    }
    __syncthreads();
#pragma unroll
    for (int kk = 0; kk < 4; ++kk) {
      const bf16x8 af = *reinterpret_cast<const bf16x8*>(&At[wv * 16 + m][kk * 32 + q * 8]);
#pragma unroll
      for (int c = 0; c < 4; ++c) {
        const bf16x8 bf = *reinterpret_cast<const bf16x8*>(&Bts[c * 16 + m][kk * 32 + q * 8]);
        acc[c] = MFMA16(af, bf, acc[c]);
      }
    }
  }
#pragma unroll
  for (int r2 = 0; r2 < 4; ++r2)
#pragma unroll
    for (int c = 0; c < 4; ++c) {
      const long row = m0 + wv * 16 + q * 4 + r2;
      const long col = n0 + c * 16 + m;
      xrow[row * DM + col] = acc[c][r2] + (float)hb[row * DM + col];
    }
}

// ---------------------------------------------------------------------------
// K5: LayerNorm rows of xrow -> out (validated rounds 4-6).
// ---------------------------------------------------------------------------
__global__ __launch_bounds__(256) void ln_out(const float* __restrict__ xrow,
                                              const __bf16* __restrict__ gamma,
                                              const __bf16* __restrict__ beta,
                                              const int* __restrict__ flag,
                                              void* __restrict__ out) {
  const int f32 = flag[0];
  const int r = blockIdx.x;
  const int tid = threadIdx.x;
  __shared__ float red[256];
  const float x0 = xrow[(long)r * DM + tid];
  const float x1 = xrow[(long)r * DM + tid + 256];

  red[tid] = x0 + x1; __syncthreads();
  for (int s = 128; s > 0; s >>= 1) { if (tid < s) red[tid] += red[tid + s]; __syncthreads(); }
  const float mu = red[0] * (1.f / 512.f); __syncthreads();
  red[tid] = x0 * x0 + x1 * x1; __syncthreads();
  for (int s = 128; s > 0; s >>= 1) { if (tid < s) red[tid] += red[tid + s]; __syncthreads(); }
  const float var = red[0] * (1.f / 512.f) - mu * mu; __syncthreads();
  const float rstd = rsqrtf(var + 1e-5f);

  stmix(out, (long)r * DM + tid,
        (x0 - mu) * rstd * (float)gamma[tid] + (float)beta[tid], f32);
  stmix(out, (long)r * DM + tid + 256,
        (x1 - mu) * rstd * (float)gamma[tid + 256] + (float)beta[tid + 256], f32);
}

// ---------------------------------------------------------------------------
extern "C" void kernel_launch(void* const* d_in, const int* in_sizes, int n_in,
                              void* d_out, int out_size, void* d_ws, size_t ws_size,
                              hipStream_t stream) {
  (void)in_sizes; (void)n_in; (void)out_size; (void)ws_size;
  // Workspace layout (bytes) — unchanged from rounds 5/6:
  //   qkv   bf16 [8192,2048]   @ 0           33,554,432
  //   flag  int                @ 33,554,432  256
  //   wt    bf16 [2048,512]    @ 33,554,688  2,097,152   (w_qkv^T)
  //   wot   bf16 [512,512]     @ 35,651,840  524,288     (w_o^T)
  //   att   bf16 [8192,512]    @ 36,176,128  8,388,608
  //   vt    bf16 [256,64,256]  @ 44,564,736  8,388,608
  //   hb    bf16 [8192,512]    @ 52,953,344  8,388,608
  //   projT bf16 [256,64]      @ 61,341,952  32,768
  //   pi0b/pi1b/gamb/betb      @ 61,374,720  ...
  //   qf    bf16 [256,256,512] @ 61,384,960  67,108,864
  //   kf    bf16 [256,256,512] @ 128,493,824 67,108,864
  //   xrow  f32  [8192,512]    @ 61,384,960  (aliases qf; used after flash)
  char* ws = (char*)d_ws;
  __bf16* qkv   = (__bf16*)ws;
  int*    flag  = (int*)(ws + 33554432);
  __bf16* wt    = (__bf16*)(ws + 33554688);
  __bf16* wot   = (__bf16*)(ws + 35651840);
  __bf16* att   = (__bf16*)(ws + 36176128);
  __bf16* vt    = (__bf16*)(ws + 44564736);
  __bf16* hb    = (__bf16*)(ws + 52953344);
  __bf16* projT = (__bf16*)(ws + 61341952);
  __bf16* pi0b  = (__bf16*)(ws + 61374720);
  __bf16* pi1b  = (__bf16*)(ws + 61378816);
  __bf16* gamb  = (__bf16*)(ws + 61382912);
  __bf16* betb  = (__bf16*)(ws + 61383936);
  __bf16* qf    = (__bf16*)(ws + 61384960);
  __bf16* kf    = (__bf16*)(ws + 128493824);
  float*  xrow  = (float*)(ws + 61384960);   // aliases qf

  prep<<<PREP_BLOCKS, 256, 0, stream>>>(d_in[0], d_in[1], d_in[2], d_in[7],
                                        d_in[5], d_in[6], d_in[3], d_in[4],
                                        flag, hb, wt, wot, projT,
                                        pi0b, pi1b, gamb, betb);
  gemm_h_wqkv<<<dim3(32, 128), 256, 0, stream>>>(hb, wt, qkv);
  vpack<<<dim3(4, 256), 256, 0, stream>>>(qkv, vt);
  features_mfma<<<dim3(4, 256), 256, 0, stream>>>(qkv, projT, pi0b, pi1b, qf, kf);
  flash_mfma<<<dim3(2, 256), 256, 0, stream>>>(qf, kf, vt, att);
  gemm_att_wo<<<dim3(8, 128), 256, 0, stream>>>(att, wot, hb, xrow);
  ln_out<<<dim3(ROWS), 256, 0, stream>>>(xrow, gamb, betb, flag, d_out);
}

// Round 8
// 265.950 us; speedup vs baseline: 7.3843x; 1.0433x over previous
//
#include <hip/hip_runtime.h>
#include <hip/hip_bf16.h>

// L=256, B=32, H=8, d_head=64, m=256, feature dim 2m=512, D_MODEL=512
#define L_SEQ 256
#define B_SZ  32
#define NH    8
#define DH    64
#define DM    512
#define FD    512
#define PM    256
#define ROWS  8192
#define QKVN  2048

typedef __bf16 bf16x8 __attribute__((ext_vector_type(8)));
typedef float f32x4 __attribute__((ext_vector_type(4)));
#define MFMA16(a, b, c) __builtin_amdgcn_mfma_f32_16x16x32_bf16((a), (b), (c), 0, 0, 0)

static __device__ __forceinline__ void stmix(void* p, long i, float v, int f32) {
  if (f32) ((float*)p)[i] = v;
  else     ((__bf16*)p)[i] = (__bf16)v;
}

// ---------------------------------------------------------------------------
// P0: prep — probe + h-cvt + 3 transposes + tiny cvts in one launch
// (validated round 7). Every block re-derives the dtype flag inline.
// ---------------------------------------------------------------------------
#define PREP_HB   2048
#define PREP_WT   256
#define PREP_WOT  64
#define PREP_PJ   4
#define PREP_TINY 1
#define PREP_BLOCKS (PREP_HB + PREP_WT + PREP_WOT + PREP_PJ + PREP_TINY)

__global__ __launch_bounds__(256) void prep(
    const void* __restrict__ h, const void* __restrict__ wqkv,
    const void* __restrict__ wo, const void* __restrict__ proj,
    const void* __restrict__ pi0, const void* __restrict__ pi1,
    const void* __restrict__ gam, const void* __restrict__ bet,
    int* __restrict__ flag, __bf16* __restrict__ hb, __bf16* __restrict__ wt,
    __bf16* __restrict__ wot, __bf16* __restrict__ projT,
    __bf16* __restrict__ pi0b, __bf16* __restrict__ pi1b,
    __bf16* __restrict__ gamb, __bf16* __restrict__ betb) {
  __shared__ float T[64][69];
  __shared__ int red[256];
  const int tid = threadIdx.x;
  int cnt = 0;
  {
    const unsigned short* hbits = (const unsigned short*)h;
    for (int i = 0; i < 16; ++i) {
      const unsigned short u = hbits[tid * 16 + i];
      if (((u >> 7) & 0xFF) >= 0xA0) ++cnt;
    }
  }
  red[tid] = cnt; __syncthreads();
  for (int s = 128; s > 0; s >>= 1) { if (tid < s) red[tid] += red[tid + s]; __syncthreads(); }
  const int f32 = (red[0] >= 64) ? 1 : 0;
  __syncthreads();

  const int blk = blockIdx.x;
  if (blk < PREP_HB) {
    const int i = blk * 256 + tid;
    if (f32) {
      const f32x4* s = (const f32x4*)h;
      const f32x4 a = s[i * 2], b = s[i * 2 + 1];
      bf16x8 t;
      t[0] = (__bf16)a[0]; t[1] = (__bf16)a[1]; t[2] = (__bf16)a[2]; t[3] = (__bf16)a[3];
      t[4] = (__bf16)b[0]; t[5] = (__bf16)b[1]; t[6] = (__bf16)b[2]; t[7] = (__bf16)b[3];
      *reinterpret_cast<bf16x8*>(hb + (long)i * 8) = t;
    } else {
      *reinterpret_cast<bf16x8*>(hb + (long)i * 8) = ((const bf16x8*)h)[i];
    }
    return;
  }
  const void* src; __bf16* dst; int M, N, n0, m0;
  if (blk < PREP_HB + PREP_WT) {
    const int x = blk - PREP_HB;
    src = wqkv; dst = wt; M = 512; N = 2048; n0 = (x & 31) * 64; m0 = (x >> 5) * 64;
  } else if (blk < PREP_HB + PREP_WT + PREP_WOT) {
    const int x = blk - PREP_HB - PREP_WT;
    src = wo; dst = wot; M = 512; N = 512; n0 = (x & 7) * 64; m0 = (x >> 3) * 64;
  } else if (blk < PREP_HB + PREP_WT + PREP_WOT + PREP_PJ) {
    const int x = blk - PREP_HB - PREP_WT - PREP_WOT;
    src = proj; dst = projT; M = 64; N = 256; n0 = x * 64; m0 = 0;
  } else {
    if (tid == 0) flag[0] = f32;
    if (f32) {
      const float* s0 = (const float*)pi0; const float* s1 = (const float*)pi1;
      const float* s2 = (const float*)gam; const float* s3 = (const float*)bet;
      for (int i = tid; i < NH * 256; i += 256) { pi0b[i] = (__bf16)s0[i]; pi1b[i] = (__bf16)s1[i]; }
      for (int i = tid; i < DM; i += 256)      { gamb[i] = (__bf16)s2[i]; betb[i] = (__bf16)s3[i]; }
    } else {
      const __bf16* s0 = (const __bf16*)pi0; const __bf16* s1 = (const __bf16*)pi1;
      const __bf16* s2 = (const __bf16*)gam; const __bf16* s3 = (const __bf16*)bet;
      for (int i = tid; i < NH * 256; i += 256) { pi0b[i] = s0[i]; pi1b[i] = s1[i]; }
      for (int i = tid; i < DM; i += 256)      { gamb[i] = s2[i]; betb[i] = s3[i]; }
    }
    return;
  }
  if (f32) {
    const float* s = (const float*)src;
#pragma unroll
    for (int rep = 0; rep < 16; ++rep) {
      const int i = rep * 4 + (tid >> 6), j = tid & 63;
      T[i][j] = s[(long)(m0 + i) * N + n0 + j];
    }
  } else {
    const __bf16* s = (const __bf16*)src;
#pragma unroll
    for (int rep = 0; rep < 16; ++rep) {
      const int i = rep * 4 + (tid >> 6), j = tid & 63;
      T[i][j] = (float)s[(long)(m0 + i) * N + n0 + j];
    }
  }
  __syncthreads();
#pragma unroll
  for (int rep = 0; rep < 16; ++rep) {
    const int i = rep * 4 + (tid >> 6), j = tid & 63;
    dst[(long)(n0 + i) * M + m0 + j] = (__bf16)T[j][i];
  }
}

// ---------------------------------------------------------------------------
// K1: qkv = hb @ w_qkv via MFMA with register prefetch (validated round 7).
// ---------------------------------------------------------------------------
__global__ __launch_bounds__(256) void gemm_h_wqkv(const __bf16* __restrict__ A,
                                                   const __bf16* __restrict__ Bt,
                                                   __bf16* __restrict__ C) {
  __shared__ __bf16 At[64][136];
  __shared__ __bf16 Bts[64][136];
  const int n0 = blockIdx.x * 64, m0 = blockIdx.y * 64;
  const int tid = threadIdx.x, lane = tid & 63, wv = tid >> 6;
  const int m = lane & 15, q = lane >> 4;
  const int r = tid >> 2, c0 = (tid & 3) * 32;
  const __bf16* ap = A + (long)(m0 + r) * DM + c0;
  const __bf16* bp = Bt + (long)(n0 + r) * DM + c0;
  f32x4 acc[4];
#pragma unroll
  for (int i = 0; i < 4; ++i) acc[i] = f32x4{0.f, 0.f, 0.f, 0.f};

  bf16x8 ar[4], br[4];
#pragma unroll
  for (int j = 0; j < 4; ++j) {
    ar[j] = *reinterpret_cast<const bf16x8*>(ap + j * 8);
    br[j] = *reinterpret_cast<const bf16x8*>(bp + j * 8);
  }
  for (int k0 = 0; k0 < DM; k0 += 128) {
    __syncthreads();
#pragma unroll
    for (int j = 0; j < 4; ++j) {
      *reinterpret_cast<bf16x8*>(&At[r][c0 + j * 8]) = ar[j];
      *reinterpret_cast<bf16x8*>(&Bts[r][c0 + j * 8]) = br[j];
    }
    if (k0 + 128 < DM) {
#pragma unroll
      for (int j = 0; j < 4; ++j) {
        ar[j] = *reinterpret_cast<const bf16x8*>(ap + k0 + 128 + j * 8);
        br[j] = *reinterpret_cast<const bf16x8*>(bp + k0 + 128 + j * 8);
      }
    }
    __syncthreads();
#pragma unroll
    for (int kk = 0; kk < 4; ++kk) {
      const bf16x8 af = *reinterpret_cast<const bf16x8*>(&At[wv * 16 + m][kk * 32 + q * 8]);
#pragma unroll
      for (int c = 0; c < 4; ++c) {
        const bf16x8 bf = *reinterpret_cast<const bf16x8*>(&Bts[c * 16 + m][kk * 32 + q * 8]);
        acc[c] = MFMA16(af, bf, acc[c]);
      }
    }
  }
#pragma unroll
  for (int r2 = 0; r2 < 4; ++r2)
#pragma unroll
    for (int c = 0; c < 4; ++c)
      C[(long)(m0 + wv * 16 + q * 4 + r2) * QKVN + n0 + c * 16 + m] = (__bf16)acc[c][r2];
}

// ---------------------------------------------------------------------------
// K2: Performer features v3. MFMA + in-register softmax (structure validated
// rounds 5-7). Round-8 changes:
//  (a) PERMUTED feature layout col' = m*16 + c — a fixed permutation applied
//      to BOTH qf and kf is invariant for all downstream dot products, and
//      makes each lane's 16 columns contiguous -> bf16x8 vector stores
//      (256 scalar 2B stores/thread -> 32 16B stores).
//  (b) e2 = exp(-2mx) * rcp(e1): e1 cached in the dead accumulator, write
//      pass uses rcp instead of 2 more expf (4 -> 3 transcendentals/elem).
// ---------------------------------------------------------------------------
__global__ __launch_bounds__(256) void features_mfma(const __bf16* __restrict__ qkv,
                                                     const __bf16* __restrict__ projT,
                                                     const __bf16* __restrict__ pi0,
                                                     const __bf16* __restrict__ pi1,
                                                     __bf16* __restrict__ qf,
                                                     __bf16* __restrict__ kf) {
  const int l0 = blockIdx.x * 64;
  const int bh = blockIdx.y;
  const int h = bh & 7, b = bh >> 3;
  const int tid = threadIdx.x, lane = tid & 63, wv = tid >> 6;
  const int m = lane & 15, q = lane >> 4;
  __shared__ __bf16 Bs[256][72];     // projT rows (n=proj col, k=d)
  __shared__ __bf16 As[3][64][72];   // q / k1 / k2 tiles: 64 l-rows x 64 d

  {
    const __bf16* p = projT + (long)tid * 64;
#pragma unroll
    for (int j = 0; j < 8; ++j)
      *reinterpret_cast<bf16x8*>(&Bs[tid][j * 8]) = *reinterpret_cast<const bf16x8*>(p + j * 8);
  }
  {
    const int r = tid >> 2, c0 = (tid & 3) * 16;
    const __bf16* ap = qkv + (long)((l0 + r) * B_SZ + b) * QKVN + h * 256 + c0;
#pragma unroll
    for (int t3 = 0; t3 < 3; ++t3) {
      *reinterpret_cast<bf16x8*>(&As[t3][r][c0]) =
          *reinterpret_cast<const bf16x8*>(ap + t3 * 64);
      *reinterpret_cast<bf16x8*>(&As[t3][r][c0 + 8]) =
          *reinterpret_cast<const bf16x8*>(ap + t3 * 64 + 8);
    }
  }
  float p0w[4], p1w[4];
#pragma unroll
  for (int r = 0; r < 4; ++r) {
    const int l = l0 + wv * 16 + q * 4 + r;
    p0w[r] = (float)pi0[h * 256 + l];
    p1w[r] = (float)pi1[h * 256 + l];
  }
  const float SQ = 0.35355339f;      // 64^-0.25
  const float SK2 = 0.24748737f;     // 0.7 * 64^-0.25
  __syncthreads();                   // the only barrier

  // ---- phase Q ----
  {
    f32x4 acc[16];
#pragma unroll
    for (int c = 0; c < 16; ++c) acc[c] = f32x4{0.f, 0.f, 0.f, 0.f};
#pragma unroll
    for (int kk = 0; kk < 2; ++kk) {
      const bf16x8 af = *reinterpret_cast<const bf16x8*>(&As[0][wv * 16 + m][kk * 32 + q * 8]);
#pragma unroll
      for (int c = 0; c < 16; ++c) {
        const bf16x8 bf = *reinterpret_cast<const bf16x8*>(&Bs[c * 16 + m][kk * 32 + q * 8]);
        acc[c] = MFMA16(af, bf, acc[c]);
      }
    }
    float mx[4] = {0.f, 0.f, 0.f, 0.f}, sm[4] = {0.f, 0.f, 0.f, 0.f};
#pragma unroll
    for (int c = 0; c < 16; ++c)
#pragma unroll
      for (int r = 0; r < 4; ++r) mx[r] = fmaxf(mx[r], fabsf(acc[c][r] * SQ));
#pragma unroll
    for (int msk = 1; msk < 16; msk <<= 1)
#pragma unroll
      for (int r = 0; r < 4; ++r) mx[r] = fmaxf(mx[r], __shfl_xor(mx[r], msk));
    float C2[4];
#pragma unroll
    for (int r = 0; r < 4; ++r) C2[r] = __expf(-2.f * mx[r]);
    // sum pass: e1 cached into acc; e2 = C2 * rcp(e1)
#pragma unroll
    for (int c = 0; c < 16; ++c)
#pragma unroll
      for (int r = 0; r < 4; ++r) {
        const float e1 = __expf(acc[c][r] * SQ - mx[r]);
        sm[r] += e1 + C2[r] * __builtin_amdgcn_rcpf(e1);
        acc[c][r] = e1;
      }
#pragma unroll
    for (int msk = 1; msk < 16; msk <<= 1)
#pragma unroll
      for (int r = 0; r < 4; ++r) sm[r] += __shfl_xor(sm[r], msk);

    const long base = ((long)bh * 256 + l0 + wv * 16 + q * 4) * FD + m * 16;
#pragma unroll
    for (int r = 0; r < 4; ++r) {
      const float inv = __builtin_amdgcn_rcpf(sm[r]);
      const float K2 = C2[r] * inv;
      __bf16 pk[16], nk[16];
#pragma unroll
      for (int c = 0; c < 16; ++c) {
        const float e1 = acc[c][r];
        pk[c] = (__bf16)(e1 * inv);
        nk[c] = (__bf16)(K2 * __builtin_amdgcn_rcpf(e1));
      }
      __bf16* op = qf + base + (long)r * FD;
      *reinterpret_cast<bf16x8*>(op)           = *reinterpret_cast<bf16x8*>(&pk[0]);
      *reinterpret_cast<bf16x8*>(op + 8)       = *reinterpret_cast<bf16x8*>(&pk[8]);
      *reinterpret_cast<bf16x8*>(op + 256)     = *reinterpret_cast<bf16x8*>(&nk[0]);
      *reinterpret_cast<bf16x8*>(op + 256 + 8) = *reinterpret_cast<bf16x8*>(&nk[8]);
    }
  }

  // ---- phase K1+K2 (fused, single kf write pass) ----
  {
    f32x4 acc1[16], acc2[16];
#pragma unroll
    for (int c = 0; c < 16; ++c) {
      acc1[c] = f32x4{0.f, 0.f, 0.f, 0.f};
      acc2[c] = f32x4{0.f, 0.f, 0.f, 0.f};
    }
#pragma unroll
    for (int kk = 0; kk < 2; ++kk) {
      const bf16x8 a1 = *reinterpret_cast<const bf16x8*>(&As[1][wv * 16 + m][kk * 32 + q * 8]);
      const bf16x8 a2 = *reinterpret_cast<const bf16x8*>(&As[2][wv * 16 + m][kk * 32 + q * 8]);
#pragma unroll
      for (int c = 0; c < 16; ++c) {
        const bf16x8 bf = *reinterpret_cast<const bf16x8*>(&Bs[c * 16 + m][kk * 32 + q * 8]);
        acc1[c] = MFMA16(a1, bf, acc1[c]);
        acc2[c] = MFMA16(a2, bf, acc2[c]);
      }
    }
    float mx1[4] = {0.f, 0.f, 0.f, 0.f}, sm1[4] = {0.f, 0.f, 0.f, 0.f};
    float mx2[4] = {0.f, 0.f, 0.f, 0.f}, sm2[4] = {0.f, 0.f, 0.f, 0.f};
#pragma unroll
    for (int c = 0; c < 16; ++c)
#pragma unroll
      for (int r = 0; r < 4; ++r) {
        mx1[r] = fmaxf(mx1[r], fabsf(acc1[c][r] * SQ));
        mx2[r] = fmaxf(mx2[r], fabsf(acc2[c][r] * SK2));
      }
#pragma unroll
    for (int msk = 1; msk < 16; msk <<= 1)
#pragma unroll
      for (int r = 0; r < 4; ++r) {
        mx1[r] = fmaxf(mx1[r], __shfl_xor(mx1[r], msk));
        mx2[r] = fmaxf(mx2[r], __shfl_xor(mx2[r], msk));
      }
    float C21[4], C22[4];
#pragma unroll
    for (int r = 0; r < 4; ++r) {
      C21[r] = __expf(-2.f * mx1[r]);
      C22[r] = __expf(-2.f * mx2[r]);
    }
#pragma unroll
    for (int c = 0; c < 16; ++c)
#pragma unroll
      for (int r = 0; r < 4; ++r) {
        const float e11 = __expf(acc1[c][r] * SQ - mx1[r]);
        const float e12 = __expf(acc2[c][r] * SK2 - mx2[r]);
        sm1[r] += e11 + C21[r] * __builtin_amdgcn_rcpf(e11);
        sm2[r] += e12 + C22[r] * __builtin_amdgcn_rcpf(e12);
        acc1[c][r] = e11;
        acc2[c][r] = e12;
      }
#pragma unroll
    for (int msk = 1; msk < 16; msk <<= 1)
#pragma unroll
      for (int r = 0; r < 4; ++r) {
        sm1[r] += __shfl_xor(sm1[r], msk);
        sm2[r] += __shfl_xor(sm2[r], msk);
      }
    const long base = ((long)bh * 256 + l0 + wv * 16 + q * 4) * FD + m * 16;
#pragma unroll
    for (int r = 0; r < 4; ++r) {
      const float w1 = p0w[r] * __builtin_amdgcn_rcpf(sm1[r]);
      const float w2 = p1w[r] * __builtin_amdgcn_rcpf(sm2[r]);
      const float K1 = C21[r] * w1, K2 = C22[r] * w2;
      __bf16 pk[16], nk[16];
#pragma unroll
      for (int c = 0; c < 16; ++c) {
        const float e11 = acc1[c][r], e12 = acc2[c][r];
        pk[c] = (__bf16)(w1 * e11 + w2 * e12);
        nk[c] = (__bf16)(K1 * __builtin_amdgcn_rcpf(e11) + K2 * __builtin_amdgcn_rcpf(e12));
      }
      __bf16* op = kf + base + (long)r * FD;
      *reinterpret_cast<bf16x8*>(op)           = *reinterpret_cast<bf16x8*>(&pk[0]);
      *reinterpret_cast<bf16x8*>(op + 8)       = *reinterpret_cast<bf16x8*>(&pk[8]);
      *reinterpret_cast<bf16x8*>(op + 256)     = *reinterpret_cast<bf16x8*>(&nk[0]);
      *reinterpret_cast<bf16x8*>(op + 256 + 8) = *reinterpret_cast<bf16x8*>(&nk[8]);
    }
  }
}

// ---------------------------------------------------------------------------
// K2b: pack V transposed per head: vt[bh][d][s] (validated).
// ---------------------------------------------------------------------------
__global__ __launch_bounds__(256) void vpack(const __bf16* __restrict__ qkv,
                                             __bf16* __restrict__ vt) {
  const int s0 = blockIdx.x * 64;
  const int bh = blockIdx.y;
  const int h = bh & 7, b = bh >> 3;
  __shared__ __bf16 T[64][72];
  const int tid = threadIdx.x;
  {
    const int s = tid >> 2, d0 = (tid & 3) * 16;
    const __bf16* vp = qkv + ((long)((s0 + s) * B_SZ + b)) * QKVN + h * 256 + 192 + d0;
#pragma unroll
    for (int j = 0; j < 16; ++j) T[d0 + j][s] = vp[j];
  }
  __syncthreads();
  {
    const int d = tid >> 2, sc = (tid & 3) * 16;
    __bf16* op = vt + ((long)bh * 64 + d) * 256 + s0 + sc;
    *reinterpret_cast<bf16x8*>(op)     = *reinterpret_cast<const bf16x8*>(&T[d][sc]);
    *reinterpret_cast<bf16x8*>(op + 8) = *reinterpret_cast<const bf16x8*>(&T[d][sc + 8]);
  }
}

// ---------------------------------------------------------------------------
// K3: MFMA flash causal linear attention — paired t-tiles + register prefetch
// (validated round 7).
// ---------------------------------------------------------------------------
__global__ __launch_bounds__(256, 2) void flash_mfma(const __bf16* __restrict__ qf,
                                                     const __bf16* __restrict__ kf,
                                                     const __bf16* __restrict__ vt,
                                                     __bf16* __restrict__ att) {
  const int pr = blockIdx.x;              // 0:{0,3}  1:{1,2}
  const int bh = blockIdx.y;
  const int h = bh & 7, b = bh >> 3;
  const int tid = threadIdx.x, lane = tid & 63, wv = tid >> 6;
  const int m = lane & 15, q = lane >> 4;
  const int tA = pr, tB = 3 - pr;
  __shared__ __bf16 Kc[64][136];
  __shared__ __bf16 Vt[80][72];
  __shared__ __bf16 Pt[64][72];

  bf16x8 qA[16], qB[16];
  {
    const __bf16* qpA = qf + ((long)(bh * 256 + tA * 64 + wv * 16 + m)) * FD + q * 8;
    const __bf16* qpB = qf + ((long)(bh * 256 + tB * 64 + wv * 16 + m)) * FD + q * 8;
#pragma unroll
    for (int ks = 0; ks < 16; ++ks) {
      qA[ks] = *reinterpret_cast<const bf16x8*>(qpA + ks * 32);
      qB[ks] = *reinterpret_cast<const bf16x8*>(qpB + ks * 32);
    }
  }
  f32x4 oA[5], oB[5];
#pragma unroll
  for (int i = 0; i < 5; ++i) { oA[i] = f32x4{0.f, 0.f, 0.f, 0.f}; oB[i] = oA[i]; }

  if (tid < 64) Vt[64][tid] = (__bf16)1.0f;
  for (int z = tid; z < 15 * 64; z += 256) Vt[65 + (z >> 6)][z & 63] = (__bf16)0.f;

  const int vrow = tid >> 2, vc0 = (tid & 3) * 16;
  const int krow = tid >> 2, kc0 = (tid & 3) * 32;
  const __bf16* vbase = vt + ((long)bh * 64 + vrow) * 256 + vc0;
  const __bf16* kbase = kf + ((long)(bh * 256 + krow)) * FD + kc0;
  bf16x8 vr0, vr1, kr[4];
  vr0 = *reinterpret_cast<const bf16x8*>(vbase);
  vr1 = *reinterpret_cast<const bf16x8*>(vbase + 8);
#pragma unroll
  for (int j = 0; j < 4; ++j) kr[j] = *reinterpret_cast<const bf16x8*>(kbase + j * 8);

  for (int st = 0; st <= tB; ++st) {
    const bool aA = (st <= tA);
    f32x4 sA[4], sB[4];
#pragma unroll
    for (int i = 0; i < 4; ++i) { sA[i] = f32x4{0.f, 0.f, 0.f, 0.f}; sB[i] = sA[i]; }
#pragma unroll
    for (int ch = 0; ch < 4; ++ch) {
      __syncthreads();
      if (ch == 0) {
        *reinterpret_cast<bf16x8*>(&Vt[vrow][vc0])     = vr0;
        *reinterpret_cast<bf16x8*>(&Vt[vrow][vc0 + 8]) = vr1;
      }
#pragma unroll
      for (int j = 0; j < 4; ++j)
        *reinterpret_cast<bf16x8*>(&Kc[krow][kc0 + j * 8]) = kr[j];
      if (ch < 3) {
        const __bf16* kp = kbase + (long)st * 64 * FD + (ch + 1) * 128;
#pragma unroll
        for (int j = 0; j < 4; ++j) kr[j] = *reinterpret_cast<const bf16x8*>(kp + j * 8);
      } else if (st < tB) {
        const __bf16* kp = kbase + (long)(st + 1) * 64 * FD;
#pragma unroll
        for (int j = 0; j < 4; ++j) kr[j] = *reinterpret_cast<const bf16x8*>(kp + j * 8);
        vr0 = *reinterpret_cast<const bf16x8*>(vbase + (st + 1) * 64);
        vr1 = *reinterpret_cast<const bf16x8*>(vbase + (st + 1) * 64 + 8);
      }
      __syncthreads();
#pragma unroll
      for (int kk = 0; kk < 4; ++kk) {
#pragma unroll
        for (int c = 0; c < 4; ++c) {
          const bf16x8 bf = *reinterpret_cast<const bf16x8*>(&Kc[c * 16 + m][kk * 32 + q * 8]);
          sB[c] = MFMA16(qB[ch * 4 + kk], bf, sB[c]);
          if (aA) sA[c] = MFMA16(qA[ch * 4 + kk], bf, sA[c]);
        }
      }
    }
    {
      const bool mask = (st == tB);
#pragma unroll
      for (int c = 0; c < 4; ++c)
#pragma unroll
        for (int r = 0; r < 4; ++r) {
          const int row = wv * 16 + q * 4 + r, col = c * 16 + m;
          Pt[row][col] = (__bf16)((mask && col > row) ? 0.f : sB[c][r]);
        }
#pragma unroll
      for (int kk = 0; kk < 2; ++kk) {
        const bf16x8 pf = *reinterpret_cast<const bf16x8*>(&Pt[wv * 16 + m][kk * 32 + q * 8]);
#pragma unroll
        for (int c = 0; c < 5; ++c) {
          const bf16x8 vf = *reinterpret_cast<const bf16x8*>(&Vt[c * 16 + m][kk * 32 + q * 8]);
          oB[c] = MFMA16(pf, vf, oB[c]);
        }
      }
    }
    if (aA) {
      const bool mask = (st == tA);
#pragma unroll
      for (int c = 0; c < 4; ++c)
#pragma unroll
        for (int r = 0; r < 4; ++r) {
          const int row = wv * 16 + q * 4 + r, col = c * 16 + m;
          Pt[row][col] = (__bf16)((mask && col > row) ? 0.f : sA[c][r]);
        }
#pragma unroll
      for (int kk = 0; kk < 2; ++kk) {
        const bf16x8 pf = *reinterpret_cast<const bf16x8*>(&Pt[wv * 16 + m][kk * 32 + q * 8]);
#pragma unroll
        for (int c = 0; c < 5; ++c) {
          const bf16x8 vf = *reinterpret_cast<const bf16x8*>(&Vt[c * 16 + m][kk * 32 + q * 8]);
          oA[c] = MFMA16(pf, vf, oA[c]);
        }
      }
    }
  }
#pragma unroll
  for (int r = 0; r < 4; ++r) {
    const float denB = __shfl(oB[4][r], (lane & 48));
    const float invB = 0.125f / (denB + 1e-5f);          // SCALE=64^-0.5, EPS
    const int rowB = tB * 64 + wv * 16 + q * 4 + r;
#pragma unroll
    for (int c = 0; c < 4; ++c)
      att[((long)(rowB * B_SZ + b)) * DM + h * DH + c * 16 + m] = (__bf16)(oB[c][r] * invB);
    const float denA = __shfl(oA[4][r], (lane & 48));
    const float invA = 0.125f / (denA + 1e-5f);
    const int rowA = tA * 64 + wv * 16 + q * 4 + r;
#pragma unroll
    for (int c = 0; c < 4; ++c)
      att[((long)(rowA * B_SZ + b)) * DM + h * DH + c * 16 + m] = (__bf16)(oA[c][r] * invA);
  }
}

// ---------------------------------------------------------------------------
// K4: xrow = hb + att @ w_o (f32 out), MFMA with register prefetch.
// ---------------------------------------------------------------------------
__global__ __launch_bounds__(256) void gemm_att_wo(const __bf16* __restrict__ A,
                                                   const __bf16* __restrict__ Bt,
                                                   const __bf16* __restrict__ hb,
                                                   float* __restrict__ xrow) {
  __shared__ __bf16 At[64][136];
  __shared__ __bf16 Bts[64][136];
  const int n0 = blockIdx.x * 64, m0 = blockIdx.y * 64;
  const int tid = threadIdx.x, lane = tid & 63, wv = tid >> 6;
  const int m = lane & 15, q = lane >> 4;
  const int r = tid >> 2, c0 = (tid & 3) * 32;
  const __bf16* ap = A + (long)(m0 + r) * DM + c0;
  const __bf16* bp = Bt + (long)(n0 + r) * DM + c0;
  f32x4 acc[4];
#pragma unroll
  for (int i = 0; i < 4; ++i) acc[i] = f32x4{0.f, 0.f, 0.f, 0.f};

  bf16x8 ar[4], br[4];
#pragma unroll
  for (int j = 0; j < 4; ++j) {
    ar[j] = *reinterpret_cast<const bf16x8*>(ap + j * 8);
    br[j] = *reinterpret_cast<const bf16x8*>(bp + j * 8);
  }
  for (int k0 = 0; k0 < DM; k0 += 128) {
    __syncthreads();
#pragma unroll
    for (int j = 0; j < 4; ++j) {
      *reinterpret_cast<bf16x8*>(&At[r][c0 + j * 8]) = ar[j];
      *reinterpret_cast<bf16x8*>(&Bts[r][c0 + j * 8]) = br[j];
    }
    if (k0 + 128 < DM) {
#pragma unroll
      for (int j = 0; j < 4; ++j) {
        ar[j] = *reinterpret_cast<const bf16x8*>(ap + k0 + 128 + j * 8);
        br[j] = *reinterpret_cast<const bf16x8*>(bp + k0 + 128 + j * 8);
      }
    }
    __syncthreads();
#pragma unroll
    for (int kk = 0; kk < 4; ++kk) {
      const bf16x8 af = *reinterpret_cast<const bf16x8*>(&At[wv * 16 + m][kk * 32 + q * 8]);
#pragma unroll
      for (int c = 0; c < 4; ++c) {
        const bf16x8 bf = *reinterpret_cast<const bf16x8*>(&Bts[c * 16 + m][kk * 32 + q * 8]);
        acc[c] = MFMA16(af, bf, acc[c]);
      }
    }
  }
#pragma unroll
  for (int r2 = 0; r2 < 4; ++r2)
#pragma unroll
    for (int c = 0; c < 4; ++c) {
      const long row = m0 + wv * 16 + q * 4 + r2;
      const long col = n0 + c * 16 + m;
      xrow[row * DM + col] = acc[c][r2] + (float)hb[row * DM + col];
    }
}

// ---------------------------------------------------------------------------
// K5: LayerNorm rows of xrow -> out (validated rounds 4-7).
// ---------------------------------------------------------------------------
__global__ __launch_bounds__(256) void ln_out(const float* __restrict__ xrow,
                                              const __bf16* __restrict__ gamma,
                                              const __bf16* __restrict__ beta,
                                              const int* __restrict__ flag,
                                              void* __restrict__ out) {
  const int f32 = flag[0];
  const int r = blockIdx.x;
  const int tid = threadIdx.x;
  __shared__ float red[256];
  const float x0 = xrow[(long)r * DM + tid];
  const float x1 = xrow[(long)r * DM + tid + 256];

  red[tid] = x0 + x1; __syncthreads();
  for (int s = 128; s > 0; s >>= 1) { if (tid < s) red[tid] += red[tid + s]; __syncthreads(); }
  const float mu = red[0] * (1.f / 512.f); __syncthreads();
  red[tid] = x0 * x0 + x1 * x1; __syncthreads();
  for (int s = 128; s > 0; s >>= 1) { if (tid < s) red[tid] += red[tid + s]; __syncthreads(); }
  const float var = red[0] * (1.f / 512.f) - mu * mu; __syncthreads();
  const float rstd = rsqrtf(var + 1e-5f);

  stmix(out, (long)r * DM + tid,
        (x0 - mu) * rstd * (float)gamma[tid] + (float)beta[tid], f32);
  stmix(out, (long)r * DM + tid + 256,
        (x1 - mu) * rstd * (float)gamma[tid + 256] + (float)beta[tid + 256], f32);
}

// ---------------------------------------------------------------------------
extern "C" void kernel_launch(void* const* d_in, const int* in_sizes, int n_in,
                              void* d_out, int out_size, void* d_ws, size_t ws_size,
                              hipStream_t stream) {
  (void)in_sizes; (void)n_in; (void)out_size; (void)ws_size;
  char* ws = (char*)d_ws;
  __bf16* qkv   = (__bf16*)ws;
  int*    flag  = (int*)(ws + 33554432);
  __bf16* wt    = (__bf16*)(ws + 33554688);
  __bf16* wot   = (__bf16*)(ws + 35651840);
  __bf16* att   = (__bf16*)(ws + 36176128);
  __bf16* vt    = (__bf16*)(ws + 44564736);
  __bf16* hb    = (__bf16*)(ws + 52953344);
  __bf16* projT = (__bf16*)(ws + 61341952);
  __bf16* pi0b  = (__bf16*)(ws + 61374720);
  __bf16* pi1b  = (__bf16*)(ws + 61378816);
  __bf16* gamb  = (__bf16*)(ws + 61382912);
  __bf16* betb  = (__bf16*)(ws + 61383936);
  __bf16* qf    = (__bf16*)(ws + 61384960);
  __bf16* kf    = (__bf16*)(ws + 128493824);
  float*  xrow  = (float*)(ws + 61384960);   // aliases qf

  prep<<<PREP_BLOCKS, 256, 0, stream>>>(d_in[0], d_in[1], d_in[2], d_in[7],
                                        d_in[5], d_in[6], d_in[3], d_in[4],
                                        flag, hb, wt, wot, projT,
                                        pi0b, pi1b, gamb, betb);
  gemm_h_wqkv<<<dim3(32, 128), 256, 0, stream>>>(hb, wt, qkv);
  vpack<<<dim3(4, 256), 256, 0, stream>>>(qkv, vt);
  features_mfma<<<dim3(4, 256), 256, 0, stream>>>(qkv, projT, pi0b, pi1b, qf, kf);
  flash_mfma<<<dim3(2, 256), 256, 0, stream>>>(qf, kf, vt, att);
  gemm_att_wo<<<dim3(8, 128), 256, 0, stream>>>(att, wot, hb, xrow);
  ln_out<<<dim3(ROWS), 256, 0, stream>>>(xrow, gamb, betb, flag, d_out);
}

// Round 9
// 257.116 us; speedup vs baseline: 7.6381x; 1.0344x over previous
//
#include <hip/hip_runtime.h>
#include <hip/hip_bf16.h>

// L=256, B=32, H=8, d_head=64, m=256, feature dim 2m=512, D_MODEL=512
#define L_SEQ 256
#define B_SZ  32
#define NH    8
#define DH    64
#define DM    512
#define FD    512
#define PM    256
#define ROWS  8192
#define QKVN  2048

typedef __bf16 bf16x8 __attribute__((ext_vector_type(8)));
typedef float f32x4 __attribute__((ext_vector_type(4)));
#define MFMA16(a, b, c) __builtin_amdgcn_mfma_f32_16x16x32_bf16((a), (b), (c), 0, 0, 0)

static __device__ __forceinline__ void stmix(void* p, long i, float v, int f32) {
  if (f32) ((float*)p)[i] = v;
  else     ((__bf16*)p)[i] = (__bf16)v;
}

// ---------------------------------------------------------------------------
// P0: prep — probe + h-cvt + 3 transposes + tiny cvts in one launch
// (validated rounds 7-8). Every block re-derives the dtype flag inline.
// ---------------------------------------------------------------------------
#define PREP_HB   2048
#define PREP_WT   256
#define PREP_WOT  64
#define PREP_PJ   4
#define PREP_TINY 1
#define PREP_BLOCKS (PREP_HB + PREP_WT + PREP_WOT + PREP_PJ + PREP_TINY)

__global__ __launch_bounds__(256) void prep(
    const void* __restrict__ h, const void* __restrict__ wqkv,
    const void* __restrict__ wo, const void* __restrict__ proj,
    const void* __restrict__ pi0, const void* __restrict__ pi1,
    const void* __restrict__ gam, const void* __restrict__ bet,
    int* __restrict__ flag, __bf16* __restrict__ hb, __bf16* __restrict__ wt,
    __bf16* __restrict__ wot, __bf16* __restrict__ projT,
    __bf16* __restrict__ pi0b, __bf16* __restrict__ pi1b,
    __bf16* __restrict__ gamb, __bf16* __restrict__ betb) {
  __shared__ float T[64][69];
  __shared__ int red[256];
  const int tid = threadIdx.x;
  int cnt = 0;
  {
    const unsigned short* hbits = (const unsigned short*)h;
    for (int i = 0; i < 16; ++i) {
      const unsigned short u = hbits[tid * 16 + i];
      if (((u >> 7) & 0xFF) >= 0xA0) ++cnt;
    }
  }
  red[tid] = cnt; __syncthreads();
  for (int s = 128; s > 0; s >>= 1) { if (tid < s) red[tid] += red[tid + s]; __syncthreads(); }
  const int f32 = (red[0] >= 64) ? 1 : 0;
  __syncthreads();

  const int blk = blockIdx.x;
  if (blk < PREP_HB) {
    const int i = blk * 256 + tid;
    if (f32) {
      const f32x4* s = (const f32x4*)h;
      const f32x4 a = s[i * 2], b = s[i * 2 + 1];
      bf16x8 t;
      t[0] = (__bf16)a[0]; t[1] = (__bf16)a[1]; t[2] = (__bf16)a[2]; t[3] = (__bf16)a[3];
      t[4] = (__bf16)b[0]; t[5] = (__bf16)b[1]; t[6] = (__bf16)b[2]; t[7] = (__bf16)b[3];
      *reinterpret_cast<bf16x8*>(hb + (long)i * 8) = t;
    } else {
      *reinterpret_cast<bf16x8*>(hb + (long)i * 8) = ((const bf16x8*)h)[i];
    }
    return;
  }
  const void* src; __bf16* dst; int M, N, n0, m0;
  if (blk < PREP_HB + PREP_WT) {
    const int x = blk - PREP_HB;
    src = wqkv; dst = wt; M = 512; N = 2048; n0 = (x & 31) * 64; m0 = (x >> 5) * 64;
  } else if (blk < PREP_HB + PREP_WT + PREP_WOT) {
    const int x = blk - PREP_HB - PREP_WT;
    src = wo; dst = wot; M = 512; N = 512; n0 = (x & 7) * 64; m0 = (x >> 3) * 64;
  } else if (blk < PREP_HB + PREP_WT + PREP_WOT + PREP_PJ) {
    const int x = blk - PREP_HB - PREP_WT - PREP_WOT;
    src = proj; dst = projT; M = 64; N = 256; n0 = x * 64; m0 = 0;
  } else {
    if (tid == 0) flag[0] = f32;
    if (f32) {
      const float* s0 = (const float*)pi0; const float* s1 = (const float*)pi1;
      const float* s2 = (const float*)gam; const float* s3 = (const float*)bet;
      for (int i = tid; i < NH * 256; i += 256) { pi0b[i] = (__bf16)s0[i]; pi1b[i] = (__bf16)s1[i]; }
      for (int i = tid; i < DM; i += 256)      { gamb[i] = (__bf16)s2[i]; betb[i] = (__bf16)s3[i]; }
    } else {
      const __bf16* s0 = (const __bf16*)pi0; const __bf16* s1 = (const __bf16*)pi1;
      const __bf16* s2 = (const __bf16*)gam; const __bf16* s3 = (const __bf16*)bet;
      for (int i = tid; i < NH * 256; i += 256) { pi0b[i] = s0[i]; pi1b[i] = s1[i]; }
      for (int i = tid; i < DM; i += 256)      { gamb[i] = s2[i]; betb[i] = s3[i]; }
    }
    return;
  }
  if (f32) {
    const float* s = (const float*)src;
#pragma unroll
    for (int rep = 0; rep < 16; ++rep) {
      const int i = rep * 4 + (tid >> 6), j = tid & 63;
      T[i][j] = s[(long)(m0 + i) * N + n0 + j];
    }
  } else {
    const __bf16* s = (const __bf16*)src;
#pragma unroll
    for (int rep = 0; rep < 16; ++rep) {
      const int i = rep * 4 + (tid >> 6), j = tid & 63;
      T[i][j] = (float)s[(long)(m0 + i) * N + n0 + j];
    }
  }
  __syncthreads();
#pragma unroll
  for (int rep = 0; rep < 16; ++rep) {
    const int i = rep * 4 + (tid >> 6), j = tid & 63;
    dst[(long)(n0 + i) * M + m0 + j] = (__bf16)T[j][i];
  }
}

// ---------------------------------------------------------------------------
// K1: qkv = hb @ w_qkv via MFMA with register prefetch (validated rounds 7-8).
// ---------------------------------------------------------------------------
__global__ __launch_bounds__(256) void gemm_h_wqkv(const __bf16* __restrict__ A,
                                                   const __bf16* __restrict__ Bt,
                                                   __bf16* __restrict__ C) {
  __shared__ __bf16 At[64][136];
  __shared__ __bf16 Bts[64][136];
  const int n0 = blockIdx.x * 64, m0 = blockIdx.y * 64;
  const int tid = threadIdx.x, lane = tid & 63, wv = tid >> 6;
  const int m = lane & 15, q = lane >> 4;
  const int r = tid >> 2, c0 = (tid & 3) * 32;
  const __bf16* ap = A + (long)(m0 + r) * DM + c0;
  const __bf16* bp = Bt + (long)(n0 + r) * DM + c0;
  f32x4 acc[4];
#pragma unroll
  for (int i = 0; i < 4; ++i) acc[i] = f32x4{0.f, 0.f, 0.f, 0.f};

  bf16x8 ar[4], br[4];
#pragma unroll
  for (int j = 0; j < 4; ++j) {
    ar[j] = *reinterpret_cast<const bf16x8*>(ap + j * 8);
    br[j] = *reinterpret_cast<const bf16x8*>(bp + j * 8);
  }
  for (int k0 = 0; k0 < DM; k0 += 128) {
    __syncthreads();
#pragma unroll
    for (int j = 0; j < 4; ++j) {
      *reinterpret_cast<bf16x8*>(&At[r][c0 + j * 8]) = ar[j];
      *reinterpret_cast<bf16x8*>(&Bts[r][c0 + j * 8]) = br[j];
    }
    if (k0 + 128 < DM) {
#pragma unroll
      for (int j = 0; j < 4; ++j) {
        ar[j] = *reinterpret_cast<const bf16x8*>(ap + k0 + 128 + j * 8);
        br[j] = *reinterpret_cast<const bf16x8*>(bp + k0 + 128 + j * 8);
      }
    }
    __syncthreads();
#pragma unroll
    for (int kk = 0; kk < 4; ++kk) {
      const bf16x8 af = *reinterpret_cast<const bf16x8*>(&At[wv * 16 + m][kk * 32 + q * 8]);
#pragma unroll
      for (int c = 0; c < 4; ++c) {
        const bf16x8 bf = *reinterpret_cast<const bf16x8*>(&Bts[c * 16 + m][kk * 32 + q * 8]);
        acc[c] = MFMA16(af, bf, acc[c]);
      }
    }
  }
#pragma unroll
  for (int r2 = 0; r2 < 4; ++r2)
#pragma unroll
    for (int c = 0; c < 4; ++c)
      C[(long)(m0 + wv * 16 + q * 4 + r2) * QKVN + n0 + c * 16 + m] = (__bf16)acc[c][r2];
}

// ---------------------------------------------------------------------------
// K2: kf-features ONLY (round-9: q-features moved into flash_mfma).
// MFMA + in-register softmax + permuted layout col'=m*16+c (validated r8).
// norm(prime(x,P)) == softmax([xP,-xP]); e2 = exp(-2mx)*rcp(e1).
// ---------------------------------------------------------------------------
__global__ __launch_bounds__(256) void features_mfma(const __bf16* __restrict__ qkv,
                                                     const __bf16* __restrict__ projT,
                                                     const __bf16* __restrict__ pi0,
                                                     const __bf16* __restrict__ pi1,
                                                     __bf16* __restrict__ kf) {
  const int l0 = blockIdx.x * 64;
  const int bh = blockIdx.y;
  const int h = bh & 7, b = bh >> 3;
  const int tid = threadIdx.x, lane = tid & 63, wv = tid >> 6;
  const int m = lane & 15, q = lane >> 4;
  __shared__ __bf16 Bs[256][72];     // projT rows (n=proj col, k=d)
  __shared__ __bf16 As[2][64][72];   // k1 / k2 tiles: 64 l-rows x 64 d

  {
    const __bf16* p = projT + (long)tid * 64;
#pragma unroll
    for (int j = 0; j < 8; ++j)
      *reinterpret_cast<bf16x8*>(&Bs[tid][j * 8]) = *reinterpret_cast<const bf16x8*>(p + j * 8);
  }
  {
    const int r = tid >> 2, c0 = (tid & 3) * 16;
    const __bf16* ap = qkv + (long)((l0 + r) * B_SZ + b) * QKVN + h * 256 + 64 + c0;
#pragma unroll
    for (int t2 = 0; t2 < 2; ++t2) {
      *reinterpret_cast<bf16x8*>(&As[t2][r][c0]) =
          *reinterpret_cast<const bf16x8*>(ap + t2 * 64);
      *reinterpret_cast<bf16x8*>(&As[t2][r][c0 + 8]) =
          *reinterpret_cast<const bf16x8*>(ap + t2 * 64 + 8);
    }
  }
  float p0w[4], p1w[4];
#pragma unroll
  for (int r = 0; r < 4; ++r) {
    const int l = l0 + wv * 16 + q * 4 + r;
    p0w[r] = (float)pi0[h * 256 + l];
    p1w[r] = (float)pi1[h * 256 + l];
  }
  const float SQ = 0.35355339f;      // 64^-0.25
  const float SK2 = 0.24748737f;     // 0.7 * 64^-0.25
  __syncthreads();                   // the only barrier

  f32x4 acc1[16], acc2[16];
#pragma unroll
  for (int c = 0; c < 16; ++c) {
    acc1[c] = f32x4{0.f, 0.f, 0.f, 0.f};
    acc2[c] = f32x4{0.f, 0.f, 0.f, 0.f};
  }
#pragma unroll
  for (int kk = 0; kk < 2; ++kk) {
    const bf16x8 a1 = *reinterpret_cast<const bf16x8*>(&As[0][wv * 16 + m][kk * 32 + q * 8]);
    const bf16x8 a2 = *reinterpret_cast<const bf16x8*>(&As[1][wv * 16 + m][kk * 32 + q * 8]);
#pragma unroll
    for (int c = 0; c < 16; ++c) {
      const bf16x8 bf = *reinterpret_cast<const bf16x8*>(&Bs[c * 16 + m][kk * 32 + q * 8]);
      acc1[c] = MFMA16(a1, bf, acc1[c]);
      acc2[c] = MFMA16(a2, bf, acc2[c]);
    }
  }
  float mx1[4] = {0.f, 0.f, 0.f, 0.f}, sm1[4] = {0.f, 0.f, 0.f, 0.f};
  float mx2[4] = {0.f, 0.f, 0.f, 0.f}, sm2[4] = {0.f, 0.f, 0.f, 0.f};
#pragma unroll
  for (int c = 0; c < 16; ++c)
#pragma unroll
    for (int r = 0; r < 4; ++r) {
      mx1[r] = fmaxf(mx1[r], fabsf(acc1[c][r] * SQ));
      mx2[r] = fmaxf(mx2[r], fabsf(acc2[c][r] * SK2));
    }
#pragma unroll
  for (int msk = 1; msk < 16; msk <<= 1)
#pragma unroll
    for (int r = 0; r < 4; ++r) {
      mx1[r] = fmaxf(mx1[r], __shfl_xor(mx1[r], msk));
      mx2[r] = fmaxf(mx2[r], __shfl_xor(mx2[r], msk));
    }
  float C21[4], C22[4];
#pragma unroll
  for (int r = 0; r < 4; ++r) {
    C21[r] = __expf(-2.f * mx1[r]);
    C22[r] = __expf(-2.f * mx2[r]);
  }
#pragma unroll
  for (int c = 0; c < 16; ++c)
#pragma unroll
    for (int r = 0; r < 4; ++r) {
      const float e11 = __expf(acc1[c][r] * SQ - mx1[r]);
      const float e12 = __expf(acc2[c][r] * SK2 - mx2[r]);
      sm1[r] += e11 + C21[r] * __builtin_amdgcn_rcpf(e11);
      sm2[r] += e12 + C22[r] * __builtin_amdgcn_rcpf(e12);
      acc1[c][r] = e11;
      acc2[c][r] = e12;
    }
#pragma unroll
  for (int msk = 1; msk < 16; msk <<= 1)
#pragma unroll
    for (int r = 0; r < 4; ++r) {
      sm1[r] += __shfl_xor(sm1[r], msk);
      sm2[r] += __shfl_xor(sm2[r], msk);
    }
  const long base = ((long)bh * 256 + l0 + wv * 16 + q * 4) * FD + m * 16;
#pragma unroll
  for (int r = 0; r < 4; ++r) {
    const float w1 = p0w[r] * __builtin_amdgcn_rcpf(sm1[r]);
    const float w2 = p1w[r] * __builtin_amdgcn_rcpf(sm2[r]);
    const float K1 = C21[r] * w1, K2 = C22[r] * w2;
    __bf16 pk[16], nk[16];
#pragma unroll
    for (int c = 0; c < 16; ++c) {
      const float e11 = acc1[c][r], e12 = acc2[c][r];
      pk[c] = (__bf16)(w1 * e11 + w2 * e12);
      nk[c] = (__bf16)(K1 * __builtin_amdgcn_rcpf(e11) + K2 * __builtin_amdgcn_rcpf(e12));
    }
    __bf16* op = kf + base + (long)r * FD;
    *reinterpret_cast<bf16x8*>(op)           = *reinterpret_cast<bf16x8*>(&pk[0]);
    *reinterpret_cast<bf16x8*>(op + 8)       = *reinterpret_cast<bf16x8*>(&pk[8]);
    *reinterpret_cast<bf16x8*>(op + 256)     = *reinterpret_cast<bf16x8*>(&nk[0]);
    *reinterpret_cast<bf16x8*>(op + 256 + 8) = *reinterpret_cast<bf16x8*>(&nk[8]);
  }
}

// ---------------------------------------------------------------------------
// K2b: pack V transposed per head: vt[bh][d][s] (validated).
// ---------------------------------------------------------------------------
__global__ __launch_bounds__(256) void vpack(const __bf16* __restrict__ qkv,
                                             __bf16* __restrict__ vt) {
  const int s0 = blockIdx.x * 64;
  const int bh = blockIdx.y;
  const int h = bh & 7, b = bh >> 3;
  __shared__ __bf16 T[64][72];
  const int tid = threadIdx.x;
  {
    const int s = tid >> 2, d0 = (tid & 3) * 16;
    const __bf16* vp = qkv + ((long)((s0 + s) * B_SZ + b)) * QKVN + h * 256 + 192 + d0;
#pragma unroll
    for (int j = 0; j < 16; ++j) T[d0 + j][s] = vp[j];
  }
  __syncthreads();
  {
    const int d = tid >> 2, sc = (tid & 3) * 16;
    __bf16* op = vt + ((long)bh * 64 + d) * 256 + s0 + sc;
    *reinterpret_cast<bf16x8*>(op)     = *reinterpret_cast<const bf16x8*>(&T[d][sc]);
    *reinterpret_cast<bf16x8*>(op + 8) = *reinterpret_cast<const bf16x8*>(&T[d][sc + 8]);
  }
}

// ---------------------------------------------------------------------------
// K3: flash with FUSED Q-features (round 9). qf never touches HBM.
// Feature phase: projT + q-slice of qkv -> MFMA -> in-register softmax
// (permuted layout, same as kf) -> LDS chunk roundtrip -> A-fragments qA/qB.
// Main loop: paired t-tiles + register prefetch (validated rounds 7-8).
// Feature-phase LDS aliases main-loop LDS via union (63.5 KB -> 2 blocks/CU).
// ---------------------------------------------------------------------------
union FlashSmem {
  struct { __bf16 Bs[256][72]; __bf16 As[64][72]; __bf16 Qtmp[64][136]; } f;
  struct { __bf16 Kc[64][136]; __bf16 Vt[80][72]; __bf16 Pt[64][72]; } mn;
};

__global__ __launch_bounds__(256, 2) void flash_mfma(const __bf16* __restrict__ qkv,
                                                     const __bf16* __restrict__ projT,
                                                     const __bf16* __restrict__ kf,
                                                     const __bf16* __restrict__ vt,
                                                     __bf16* __restrict__ att) {
  const int pr = blockIdx.x;              // 0:{0,3}  1:{1,2}
  const int bh = blockIdx.y;
  const int h = bh & 7, b = bh >> 3;
  const int tid = threadIdx.x, lane = tid & 63, wv = tid >> 6;
  const int m = lane & 15, q = lane >> 4;
  const int tA = pr, tB = 3 - pr;
  __shared__ FlashSmem S;

  // ---------------- feature phase: build qA/qB ----------------
  const float SQ = 0.35355339f;          // 64^-0.25
  {
    const __bf16* p = projT + (long)tid * 64;
#pragma unroll
    for (int j = 0; j < 8; ++j)
      *reinterpret_cast<bf16x8*>(&S.f.Bs[tid][j * 8]) =
          *reinterpret_cast<const bf16x8*>(p + j * 8);
  }
  bf16x8 qA[16], qB[16];
#pragma unroll
  for (int t2 = 0; t2 < 2; ++t2) {
    const int tt = t2 ? tB : tA;
    bf16x8* qT = t2 ? qB : qA;
    {
      const int r = tid >> 2, c0 = (tid & 3) * 16;
      const __bf16* ap = qkv + (long)((tt * 64 + r) * B_SZ + b) * QKVN + h * 256 + c0;
      *reinterpret_cast<bf16x8*>(&S.f.As[r][c0])     = *reinterpret_cast<const bf16x8*>(ap);
      *reinterpret_cast<bf16x8*>(&S.f.As[r][c0 + 8]) = *reinterpret_cast<const bf16x8*>(ap + 8);
    }
    __syncthreads();
    f32x4 acc[16];
#pragma unroll
    for (int c = 0; c < 16; ++c) acc[c] = f32x4{0.f, 0.f, 0.f, 0.f};
#pragma unroll
    for (int kk = 0; kk < 2; ++kk) {
      const bf16x8 af = *reinterpret_cast<const bf16x8*>(&S.f.As[wv * 16 + m][kk * 32 + q * 8]);
#pragma unroll
      for (int c = 0; c < 16; ++c) {
        const bf16x8 bf = *reinterpret_cast<const bf16x8*>(&S.f.Bs[c * 16 + m][kk * 32 + q * 8]);
        acc[c] = MFMA16(af, bf, acc[c]);
      }
    }
    float mx[4] = {0.f, 0.f, 0.f, 0.f}, sm[4] = {0.f, 0.f, 0.f, 0.f};
#pragma unroll
    for (int c = 0; c < 16; ++c)
#pragma unroll
      for (int r = 0; r < 4; ++r) mx[r] = fmaxf(mx[r], fabsf(acc[c][r] * SQ));
#pragma unroll
    for (int msk = 1; msk < 16; msk <<= 1)
#pragma unroll
      for (int r = 0; r < 4; ++r) mx[r] = fmaxf(mx[r], __shfl_xor(mx[r], msk));
    float C2[4];
#pragma unroll
    for (int r = 0; r < 4; ++r) C2[r] = __expf(-2.f * mx[r]);
#pragma unroll
    for (int c = 0; c < 16; ++c)
#pragma unroll
      for (int r = 0; r < 4; ++r) {
        const float e1 = __expf(acc[c][r] * SQ - mx[r]);
        sm[r] += e1 + C2[r] * __builtin_amdgcn_rcpf(e1);
        acc[c][r] = e1;
      }
#pragma unroll
    for (int msk = 1; msk < 16; msk <<= 1)
#pragma unroll
      for (int r = 0; r < 4; ++r) sm[r] += __shfl_xor(sm[r], msk);
    float inv[4], K2[4];
#pragma unroll
    for (int r = 0; r < 4; ++r) {
      inv[r] = __builtin_amdgcn_rcpf(sm[r]);
      K2[r] = C2[r] * inv[r];
    }
    // chunked LDS roundtrip: permuted C-layout -> A-fragments.
    // chunk 0: pos cols of m=0..7; 1: pos m=8..15; 2: neg m=0..7; 3: neg m=8..15
#pragma unroll
    for (int ch = 0; ch < 4; ++ch) {
      __syncthreads();                 // Qtmp free
      if ((m >> 3) == (ch & 1)) {
        const int colb = (m & 7) * 16;
        const bool neg = (ch >= 2);
#pragma unroll
        for (int r = 0; r < 4; ++r) {
          const int row = wv * 16 + q * 4 + r;
          __bf16 vv[16];
          if (!neg) {
#pragma unroll
            for (int c = 0; c < 16; ++c) vv[c] = (__bf16)(acc[c][r] * inv[r]);
          } else {
#pragma unroll
            for (int c = 0; c < 16; ++c)
              vv[c] = (__bf16)(K2[r] * __builtin_amdgcn_rcpf(acc[c][r]));
          }
          *reinterpret_cast<bf16x8*>(&S.f.Qtmp[row][colb])     = *reinterpret_cast<bf16x8*>(&vv[0]);
          *reinterpret_cast<bf16x8*>(&S.f.Qtmp[row][colb + 8]) = *reinterpret_cast<bf16x8*>(&vv[8]);
        }
      }
      __syncthreads();                 // writes visible
#pragma unroll
      for (int kk = 0; kk < 4; ++kk)
        qT[ch * 4 + kk] = *reinterpret_cast<const bf16x8*>(&S.f.Qtmp[wv * 16 + m][kk * 32 + q * 8]);
    }
  }
  __syncthreads();                     // feature region free for Vt/Pt aliasing

  // ---------------- main loop (validated rounds 7-8) ----------------
  f32x4 oA[5], oB[5];
#pragma unroll
  for (int i = 0; i < 5; ++i) { oA[i] = f32x4{0.f, 0.f, 0.f, 0.f}; oB[i] = oA[i]; }

  if (tid < 64) S.mn.Vt[64][tid] = (__bf16)1.0f;
  for (int z = tid; z < 15 * 64; z += 256) S.mn.Vt[65 + (z >> 6)][z & 63] = (__bf16)0.f;

  const int vrow = tid >> 2, vc0 = (tid & 3) * 16;
  const int krow = tid >> 2, kc0 = (tid & 3) * 32;
  const __bf16* vbase = vt + ((long)bh * 64 + vrow) * 256 + vc0;
  const __bf16* kbase = kf + ((long)(bh * 256 + krow)) * FD + kc0;
  bf16x8 vr0, vr1, kr[4];
  vr0 = *reinterpret_cast<const bf16x8*>(vbase);
  vr1 = *reinterpret_cast<const bf16x8*>(vbase + 8);
#pragma unroll
  for (int j = 0; j < 4; ++j) kr[j] = *reinterpret_cast<const bf16x8*>(kbase + j * 8);

  for (int st = 0; st <= tB; ++st) {
    const bool aA = (st <= tA);
    f32x4 sA[4], sB[4];
#pragma unroll
    for (int i = 0; i < 4; ++i) { sA[i] = f32x4{0.f, 0.f, 0.f, 0.f}; sB[i] = sA[i]; }
#pragma unroll
    for (int ch = 0; ch < 4; ++ch) {
      __syncthreads();
      if (ch == 0) {
        *reinterpret_cast<bf16x8*>(&S.mn.Vt[vrow][vc0])     = vr0;
        *reinterpret_cast<bf16x8*>(&S.mn.Vt[vrow][vc0 + 8]) = vr1;
      }
#pragma unroll
      for (int j = 0; j < 4; ++j)
        *reinterpret_cast<bf16x8*>(&S.mn.Kc[krow][kc0 + j * 8]) = kr[j];
      if (ch < 3) {
        const __bf16* kp = kbase + (long)st * 64 * FD + (ch + 1) * 128;
#pragma unroll
        for (int j = 0; j < 4; ++j) kr[j] = *reinterpret_cast<const bf16x8*>(kp + j * 8);
      } else if (st < tB) {
        const __bf16* kp = kbase + (long)(st + 1) * 64 * FD;
#pragma unroll
        for (int j = 0; j < 4; ++j) kr[j] = *reinterpret_cast<const bf16x8*>(kp + j * 8);
        vr0 = *reinterpret_cast<const bf16x8*>(vbase + (st + 1) * 64);
        vr1 = *reinterpret_cast<const bf16x8*>(vbase + (st + 1) * 64 + 8);
      }
      __syncthreads();
#pragma unroll
      for (int kk = 0; kk < 4; ++kk) {
#pragma unroll
        for (int c = 0; c < 4; ++c) {
          const bf16x8 bf = *reinterpret_cast<const bf16x8*>(&S.mn.Kc[c * 16 + m][kk * 32 + q * 8]);
          sB[c] = MFMA16(qB[ch * 4 + kk], bf, sB[c]);
          if (aA) sA[c] = MFMA16(qA[ch * 4 + kk], bf, sA[c]);
        }
      }
    }
    {
      const bool mask = (st == tB);
#pragma unroll
      for (int c = 0; c < 4; ++c)
#pragma unroll
        for (int r = 0; r < 4; ++r) {
          const int row = wv * 16 + q * 4 + r, col = c * 16 + m;
          S.mn.Pt[row][col] = (__bf16)((mask && col > row) ? 0.f : sB[c][r]);
        }
#pragma unroll
      for (int kk = 0; kk < 2; ++kk) {
        const bf16x8 pf = *reinterpret_cast<const bf16x8*>(&S.mn.Pt[wv * 16 + m][kk * 32 + q * 8]);
#pragma unroll
        for (int c = 0; c < 5; ++c) {
          const bf16x8 vf = *reinterpret_cast<const bf16x8*>(&S.mn.Vt[c * 16 + m][kk * 32 + q * 8]);
          oB[c] = MFMA16(pf, vf, oB[c]);
        }
      }
    }
    if (aA) {
      const bool mask = (st == tA);
#pragma unroll
      for (int c = 0; c < 4; ++c)
#pragma unroll
        for (int r = 0; r < 4; ++r) {
          const int row = wv * 16 + q * 4 + r, col = c * 16 + m;
          S.mn.Pt[row][col] = (__bf16)((mask && col > row) ? 0.f : sA[c][r]);
        }
#pragma unroll
      for (int kk = 0; kk < 2; ++kk) {
        const bf16x8 pf = *reinterpret_cast<const bf16x8*>(&S.mn.Pt[wv * 16 + m][kk * 32 + q * 8]);
#pragma unroll
        for (int c = 0; c < 5; ++c) {
          const bf16x8 vf = *reinterpret_cast<const bf16x8*>(&S.mn.Vt[c * 16 + m][kk * 32 + q * 8]);
          oA[c] = MFMA16(pf, vf, oA[c]);
        }
      }
    }
  }
#pragma unroll
  for (int r = 0; r < 4; ++r) {
    const float denB = __shfl(oB[4][r], (lane & 48));
    const float invB = 0.125f / (denB + 1e-5f);          // SCALE=64^-0.5, EPS
    const int rowB = tB * 64 + wv * 16 + q * 4 + r;
#pragma unroll
    for (int c = 0; c < 4; ++c)
      att[((long)(rowB * B_SZ + b)) * DM + h * DH + c * 16 + m] = (__bf16)(oB[c][r] * invB);
    const float denA = __shfl(oA[4][r], (lane & 48));
    const float invA = 0.125f / (denA + 1e-5f);
    const int rowA = tA * 64 + wv * 16 + q * 4 + r;
#pragma unroll
    for (int c = 0; c < 4; ++c)
      att[((long)(rowA * B_SZ + b)) * DM + h * DH + c * 16 + m] = (__bf16)(oA[c][r] * invA);
  }
}

// ---------------------------------------------------------------------------
// K4: xrow = hb + att @ w_o (f32 out), MFMA with register prefetch.
// ---------------------------------------------------------------------------
__global__ __launch_bounds__(256) void gemm_att_wo(const __bf16* __restrict__ A,
                                                   const __bf16* __restrict__ Bt,
                                                   const __bf16* __restrict__ hb,
                                                   float* __restrict__ xrow) {
  __shared__ __bf16 At[64][136];
  __shared__ __bf16 Bts[64][136];
  const int n0 = blockIdx.x * 64, m0 = blockIdx.y * 64;
  const int tid = threadIdx.x, lane = tid & 63, wv = tid >> 6;
  const int m = lane & 15, q = lane >> 4;
  const int r = tid >> 2, c0 = (tid & 3) * 32;
  const __bf16* ap = A + (long)(m0 + r) * DM + c0;
  const __bf16* bp = Bt + (long)(n0 + r) * DM + c0;
  f32x4 acc[4];
#pragma unroll
  for (int i = 0; i < 4; ++i) acc[i] = f32x4{0.f, 0.f, 0.f, 0.f};

  bf16x8 ar[4], br[4];
#pragma unroll
  for (int j = 0; j < 4; ++j) {
    ar[j] = *reinterpret_cast<const bf16x8*>(ap + j * 8);
    br[j] = *reinterpret_cast<const bf16x8*>(bp + j * 8);
  }
  for (int k0 = 0; k0 < DM; k0 += 128) {
    __syncthreads();
#pragma unroll
    for (int j = 0; j < 4; ++j) {
      *reinterpret_cast<bf16x8*>(&At[r][c0 + j * 8]) = ar[j];
      *reinterpret_cast<bf16x8*>(&Bts[r][c0 + j * 8]) = br[j];
    }
    if (k0 + 128 < DM) {
#pragma unroll
      for (int j = 0; j < 4; ++j) {
        ar[j] = *reinterpret_cast<const bf16x8*>(ap + k0 + 128 + j * 8);
        br[j] = *reinterpret_cast<const bf16x8*>(bp + k0 + 128 + j * 8);
      }
    }
    __syncthreads();
#pragma unroll
    for (int kk = 0; kk < 4; ++kk) {
      const bf16x8 af = *reinterpret_cast<const bf16x8*>(&At[wv * 16 + m][kk * 32 + q * 8]);
#pragma unroll
      for (int c = 0; c < 4; ++c) {
        const bf16x8 bf = *reinterpret_cast<const bf16x8*>(&Bts[c * 16 + m][kk * 32 + q * 8]);
        acc[c] = MFMA16(af, bf, acc[c]);
      }
    }
  }
#pragma unroll
  for (int r2 = 0; r2 < 4; ++r2)
#pragma unroll
    for (int c = 0; c < 4; ++c) {
      const long row = m0 + wv * 16 + q * 4 + r2;
      const long col = n0 + c * 16 + m;
      xrow[row * DM + col] = acc[c][r2] + (float)hb[row * DM + col];
    }
}

// ---------------------------------------------------------------------------
// K5: LayerNorm rows of xrow -> out (validated rounds 4-8).
// ---------------------------------------------------------------------------
__global__ __launch_bounds__(256) void ln_out(const float* __restrict__ xrow,
                                              const __bf16* __restrict__ gamma,
                                              const __bf16* __restrict__ beta,
                                              const int* __restrict__ flag,
                                              void* __restrict__ out) {
  const int f32 = flag[0];
  const int r = blockIdx.x;
  const int tid = threadIdx.x;
  __shared__ float red[256];
  const float x0 = xrow[(long)r * DM + tid];
  const float x1 = xrow[(long)r * DM + tid + 256];

  red[tid] = x0 + x1; __syncthreads();
  for (int s = 128; s > 0; s >>= 1) { if (tid < s) red[tid] += red[tid + s]; __syncthreads(); }
  const float mu = red[0] * (1.f / 512.f); __syncthreads();
  red[tid] = x0 * x0 + x1 * x1; __syncthreads();
  for (int s = 128; s > 0; s >>= 1) { if (tid < s) red[tid] += red[tid + s]; __syncthreads(); }
  const float var = red[0] * (1.f / 512.f) - mu * mu; __syncthreads();
  const float rstd = rsqrtf(var + 1e-5f);

  stmix(out, (long)r * DM + tid,
        (x0 - mu) * rstd * (float)gamma[tid] + (float)beta[tid], f32);
  stmix(out, (long)r * DM + tid + 256,
        (x1 - mu) * rstd * (float)gamma[tid + 256] + (float)beta[tid + 256], f32);
}

// ---------------------------------------------------------------------------
extern "C" void kernel_launch(void* const* d_in, const int* in_sizes, int n_in,
                              void* d_out, int out_size, void* d_ws, size_t ws_size,
                              hipStream_t stream) {
  (void)in_sizes; (void)n_in; (void)out_size; (void)ws_size;
  char* ws = (char*)d_ws;
  __bf16* qkv   = (__bf16*)ws;
  int*    flag  = (int*)(ws + 33554432);
  __bf16* wt    = (__bf16*)(ws + 33554688);
  __bf16* wot   = (__bf16*)(ws + 35651840);
  __bf16* att   = (__bf16*)(ws + 36176128);
  __bf16* vt    = (__bf16*)(ws + 44564736);
  __bf16* hb    = (__bf16*)(ws + 52953344);
  __bf16* projT = (__bf16*)(ws + 61341952);
  __bf16* pi0b  = (__bf16*)(ws + 61374720);
  __bf16* pi1b  = (__bf16*)(ws + 61378816);
  __bf16* gamb  = (__bf16*)(ws + 61382912);
  __bf16* betb  = (__bf16*)(ws + 61383936);
  __bf16* kf    = (__bf16*)(ws + 128493824);
  float*  xrow  = (float*)(ws + 61384960);   // free region (old qf slot)

  prep<<<PREP_BLOCKS, 256, 0, stream>>>(d_in[0], d_in[1], d_in[2], d_in[7],
                                        d_in[5], d_in[6], d_in[3], d_in[4],
                                        flag, hb, wt, wot, projT,
                                        pi0b, pi1b, gamb, betb);
  gemm_h_wqkv<<<dim3(32, 128), 256, 0, stream>>>(hb, wt, qkv);
  vpack<<<dim3(4, 256), 256, 0, stream>>>(qkv, vt);
  features_mfma<<<dim3(4, 256), 256, 0, stream>>>(qkv, projT, pi0b, pi1b, kf);
  flash_mfma<<<dim3(2, 256), 256, 0, stream>>>(qkv, projT, kf, vt, att);
  gemm_att_wo<<<dim3(8, 128), 256, 0, stream>>>(att, wot, hb, xrow);
  ln_out<<<dim3(ROWS), 256, 0, stream>>>(xrow, gamb, betb, flag, d_out);
}